// Round 9
// baseline (263.795 us; speedup 1.0000x reference)
//
#include <hip/hip_runtime.h>
#include <hip/hip_bf16.h>

#define N_NODES 50000
#define N_EDGES 800000
#define NFEAT 256
#define NHID 128
#define LATENT 64
#define NB 98       // coarse buckets: dst >> 9 (512 nodes each; 98*512 = 50176)
#define BSH 9
#define CT 4096     // edges per coarse tile
#define CBLK 196    // ceil(800000/4096)
#define CAP 8960    // per-bucket capacity: mean 8192 + 8.5 sigma (~90)

typedef __attribute__((ext_vector_type(8))) short bf16x8;
typedef __attribute__((ext_vector_type(4))) float f32x4;
typedef __attribute__((ext_vector_type(8))) short short8v;
typedef __attribute__((ext_vector_type(8))) unsigned short ushort8v;

__device__ inline unsigned short f2bf(float f) {
  union { float f; unsigned u; } c; c.f = f;
  unsigned r = (c.u + 0x7FFFu + ((c.u >> 16) & 1u)) >> 16;
  return (unsigned short)r;
}
__device__ inline float bf2f(unsigned short u) {
  union { unsigned u; float f; } c; c.u = ((unsigned)u) << 16;
  return c.f;
}

// ---------------------------------------------------------------------------
// Prep: W1T[n][k]=bf16(W1[k][n]) (128x256); WcT[n][k]=bf16([Wmu|Wlv][k][n])
// (128x128). Block 256 zeroes the bucket cursors.
// ---------------------------------------------------------------------------
__launch_bounds__(256)
__global__ void prep_w_kernel(const float* __restrict__ W1,
                              const float* __restrict__ Wmu,
                              const float* __restrict__ Wlv,
                              unsigned short* __restrict__ W1T,
                              unsigned short* __restrict__ WcT,
                              int* __restrict__ bcur) {
  int b = blockIdx.x;
  int t = threadIdx.x;
  if (b < 128) {
    W1T[b * NFEAT + t] = f2bf(W1[(size_t)t * NHID + b]);
  } else if (b < 256) {
    int n = b - 128;
    if (t < NHID) {
      float v = (n < 64) ? Wmu[(size_t)t * LATENT + n]
                         : Wlv[(size_t)t * LATENT + (n - 64)];
      WcT[n * NHID + t] = f2bf(v);
    }
  } else {
    if (t < 128) bcur[t] = 0;
  }
}

// ---------------------------------------------------------------------------
// GEMM1: XWb[50000][128] = bf16( x @ W1 ). 64-row tile, B direct from W1T.
// ---------------------------------------------------------------------------
__launch_bounds__(256)
__global__ void gemm1_kernel(const float* __restrict__ X,
                             const unsigned short* __restrict__ W1T,
                             unsigned short* __restrict__ XWb) {
  __shared__ short A_lds[64][40];
  const int t = threadIdx.x;
  const int lane = t & 63;
  const int wave = t >> 6;
  const int row0 = blockIdx.x * 64;
  const int l15 = lane & 15, quad = lane >> 4;
  const int srow = t >> 2, skg = t & 3;

  f32x4 acc[4][2];
#pragma unroll
  for (int i = 0; i < 4; i++)
#pragma unroll
    for (int j = 0; j < 2; j++) acc[i][j] = (f32x4){0.f, 0.f, 0.f, 0.f};

  for (int k0 = 0; k0 < NFEAT; k0 += 32) {
    int gr = row0 + srow;
    float4 v0, v1;
    if (gr < N_NODES) {
      const float* p = X + (size_t)gr * NFEAT + k0 + skg * 8;
      v0 = *(const float4*)p;
      v1 = *(const float4*)(p + 4);
    } else {
      v0 = make_float4(0.f, 0.f, 0.f, 0.f);
      v1 = v0;
    }
    short8v s;
    s[0] = f2bf(v0.x); s[1] = f2bf(v0.y); s[2] = f2bf(v0.z); s[3] = f2bf(v0.w);
    s[4] = f2bf(v1.x); s[5] = f2bf(v1.y); s[6] = f2bf(v1.z); s[7] = f2bf(v1.w);
    __syncthreads();
    *(short8v*)&A_lds[srow][skg * 8] = s;
    __syncthreads();

    bf16x8 a[4], b[2];
#pragma unroll
    for (int mt = 0; mt < 4; mt++)
      a[mt] = *(const bf16x8*)&A_lds[mt * 16 + l15][quad * 8];
#pragma unroll
    for (int nt = 0; nt < 2; nt++) {
      int n = wave * 32 + nt * 16 + l15;
      b[nt] = *(const bf16x8*)(W1T + (size_t)n * NFEAT + k0 + quad * 8);
    }
#pragma unroll
    for (int mt = 0; mt < 4; mt++)
#pragma unroll
      for (int nt = 0; nt < 2; nt++)
        acc[mt][nt] = __builtin_amdgcn_mfma_f32_16x16x32_bf16(a[mt], b[nt], acc[mt][nt], 0, 0, 0);
  }
#pragma unroll
  for (int mt = 0; mt < 4; mt++) {
#pragma unroll
    for (int reg = 0; reg < 4; reg++) {
      int gr = row0 + mt * 16 + quad * 4 + reg;
      if (gr < N_NODES) {
#pragma unroll
        for (int nt = 0; nt < 2; nt++) {
          int gc = wave * 32 + nt * 16 + l15;
          XWb[(size_t)gr * NHID + gc] = f2bf(acc[mt][nt][reg]);
        }
      }
    }
  }
}

// ---------------------------------------------------------------------------
// Single-pass coarse partition into capacity-padded buckets.
// ---------------------------------------------------------------------------
__launch_bounds__(512)
__global__ void coarse_part_kernel(const int* __restrict__ src,
                                   const int* __restrict__ dst,
                                   const float* __restrict__ ew,
                                   int* __restrict__ bcur,
                                   int2* __restrict__ part) {
  __shared__ int hist[NB], start[NB], cur[NB], gbase[NB];
  __shared__ int sc[128];
  __shared__ int2 stage[CT];
  int t = threadIdx.x;
  if (t < NB) hist[t] = 0;
  __syncthreads();
  int base = blockIdx.x * CT;
#pragma unroll
  for (int k = 0; k < 8; k++) {
    int e = base + t + k * 512;
    if (e < N_EDGES) atomicAdd(&hist[dst[e] >> BSH], 1);
  }
  __syncthreads();
  int v = (t < NB) ? hist[t] : 0;
  if (t < 128) sc[t] = v;
  __syncthreads();
  int x = v;
  for (int ofs = 1; ofs < 128; ofs <<= 1) {
    int y = (t >= ofs && t < 128) ? sc[t - ofs] : 0;
    __syncthreads();
    if (t < 128) { x += y; sc[t] = x; }
    __syncthreads();
  }
  if (t < NB) {
    int st = x - v;
    start[t] = st;
    cur[t] = st;
    gbase[t] = atomicAdd(&bcur[t], hist[t]);
  }
  __syncthreads();
#pragma unroll
  for (int k = 0; k < 8; k++) {
    int e = base + t + k * 512;
    if (e < N_EDGES) {
      int d = dst[e];
      int b = d >> BSH;
      int lp = atomicAdd(&cur[b], 1);
      stage[lp] = make_int2((src[e] << 16) | d, __float_as_int(ew[e]));
    }
  }
  __syncthreads();
  int nedge = min(CT, N_EDGES - base);
  for (int i = t; i < nedge; i += 512) {
    int2 e = stage[i];
    int b = (e.x & 0xffff) >> BSH;
    part[(size_t)b * CAP + gbase[b] + (i - start[b])] = e;
  }
}

// ---------------------------------------------------------------------------
// Per-bucket fine sort -> offs[n]=(beg,end) + dst-sorted packed edata
// (4B: (src<<16)|bf16(w)).
// ---------------------------------------------------------------------------
__launch_bounds__(512)
__global__ void fine_kernel(const int* __restrict__ bcur,
                            const int2* __restrict__ part,
                            int2* __restrict__ offs,
                            unsigned int* __restrict__ edata) {
  __shared__ int nh[512];
  __shared__ int sc[512];
  int t = threadIdx.x;
  int b = blockIdx.x;
  int base = b * CAP;
  int cnt = bcur[b];
  int nb = b << BSH;
  nh[t] = 0;
  __syncthreads();
  for (int i = t; i < cnt; i += 512) {
    int d = part[base + i].x & 0xffff;
    atomicAdd(&nh[d - nb], 1);
  }
  __syncthreads();
  int v = nh[t];
  sc[t] = v;
  __syncthreads();
  int x = v;
  for (int ofs = 1; ofs < 512; ofs <<= 1) {
    int y = (t >= ofs) ? sc[t - ofs] : 0;
    __syncthreads();
    x += y;
    sc[t] = x;
    __syncthreads();
  }
  int beg = base + (x - v);
  offs[nb + t] = make_int2(beg, beg + v);
  nh[t] = beg;
  __syncthreads();
  for (int i = t; i < cnt; i += 512) {
    int2 e = part[base + i];
    int d = e.x & 0xffff;
    int pos = atomicAdd(&nh[d - nb], 1);
    edata[pos] = (unsigned)(e.x & 0xffff0000) | (unsigned)f2bf(__int_as_float(e.y));
  }
}

// ---------------------------------------------------------------------------
// FUSED gather1 + GEMM2. Phase 1 runs TWO HALF-ROW PASSES (pass p reads only
// cols [p*64, p*64+64) = one 128B cache line per row) -> live L2 working set
// halves to 6.4MB. 8 octs x 8 lanes x 16B per edge; dual-row interleave.
// Phase 2: K=128 MFMA, B from WcT.
// ---------------------------------------------------------------------------
__launch_bounds__(256)
__global__ void g1gemm2_kernel(const unsigned short* __restrict__ XWb,
                               const int2* __restrict__ offs,
                               const unsigned int* __restrict__ edata,
                               const float* __restrict__ b1,
                               const unsigned short* __restrict__ WcT,
                               unsigned short* __restrict__ Tb) {
  __shared__ short A_lds[64][136];  // 128 cols + 8 pad
  const int t = threadIdx.x;
  const int lane = t & 63;
  const int wave = t >> 6;
  const int row0 = blockIdx.x * 64;
  const int l15 = lane & 15, quad = lane >> 4;
  const int oct = lane >> 3, l7 = lane & 7;

#pragma unroll
  for (int p = 0; p < 2; p++) {
    const int cbase = p * 64;
    float bb[8];
#pragma unroll
    for (int k = 0; k < 8; k++) bb[k] = b1[cbase + l7 * 8 + k];

    for (int rr = 0; rr < 8; rr++) {
      int rA = wave * 16 + rr;
      int rB = rA + 8;
      int gA = row0 + rA, gB = row0 + rB;
      float accA[8], accB[8];
#pragma unroll
      for (int k = 0; k < 8; k++) { accA[k] = 0.f; accB[k] = 0.f; }
      int jA = 0, eA = 0, jB = 0, eB = 0;
      if (gA < N_NODES) { int2 o = offs[gA]; jA = o.x + oct; eA = o.y; }
      if (gB < N_NODES) { int2 o = offs[gB]; jB = o.x + oct; eB = o.y; }
      // interleaved main: 2 rows x 2-deep x 8 octs = 32 edge-visits in flight
      while (jA + 8 < eA && jB + 8 < eB) {
        unsigned ea0 = edata[jA], ea1 = edata[jA + 8];
        unsigned eb0 = edata[jB], eb1 = edata[jB + 8];
        ushort8v ra0 = *(const ushort8v*)(XWb + (size_t)(ea0 >> 16) * NHID + cbase + l7 * 8);
        ushort8v ra1 = *(const ushort8v*)(XWb + (size_t)(ea1 >> 16) * NHID + cbase + l7 * 8);
        ushort8v rb0 = *(const ushort8v*)(XWb + (size_t)(eb0 >> 16) * NHID + cbase + l7 * 8);
        ushort8v rb1 = *(const ushort8v*)(XWb + (size_t)(eb1 >> 16) * NHID + cbase + l7 * 8);
        float wa0 = bf2f((unsigned short)(ea0 & 0xffffu));
        float wa1 = bf2f((unsigned short)(ea1 & 0xffffu));
        float wb0 = bf2f((unsigned short)(eb0 & 0xffffu));
        float wb1 = bf2f((unsigned short)(eb1 & 0xffffu));
#pragma unroll
        for (int k = 0; k < 8; k++) accA[k] += bf2f(ra0[k]) * wa0;
#pragma unroll
        for (int k = 0; k < 8; k++) accA[k] += bf2f(ra1[k]) * wa1;
#pragma unroll
        for (int k = 0; k < 8; k++) accB[k] += bf2f(rb0[k]) * wb0;
#pragma unroll
        for (int k = 0; k < 8; k++) accB[k] += bf2f(rb1[k]) * wb1;
        jA += 16; jB += 16;
      }
      for (; jA < eA; jA += 8) {
        unsigned ea0 = edata[jA];
        ushort8v ra0 = *(const ushort8v*)(XWb + (size_t)(ea0 >> 16) * NHID + cbase + l7 * 8);
        float wa0 = bf2f((unsigned short)(ea0 & 0xffffu));
#pragma unroll
        for (int k = 0; k < 8; k++) accA[k] += bf2f(ra0[k]) * wa0;
      }
      for (; jB < eB; jB += 8) {
        unsigned eb0 = edata[jB];
        ushort8v rb0 = *(const ushort8v*)(XWb + (size_t)(eb0 >> 16) * NHID + cbase + l7 * 8);
        float wb0 = bf2f((unsigned short)(eb0 & 0xffffu));
#pragma unroll
        for (int k = 0; k < 8; k++) accB[k] += bf2f(rb0[k]) * wb0;
      }
#pragma unroll
      for (int k = 0; k < 8; k++) {
        accA[k] += __shfl_down(accA[k], 32, 64);
        accA[k] += __shfl_down(accA[k], 16, 64);
        accA[k] += __shfl_down(accA[k], 8, 64);
        accB[k] += __shfl_down(accB[k], 32, 64);
        accB[k] += __shfl_down(accB[k], 16, 64);
        accB[k] += __shfl_down(accB[k], 8, 64);
      }
      if (lane < 8) {
        short8v sA, sB;
#pragma unroll
        for (int k = 0; k < 8; k++) {
          sA[k] = (short)f2bf(fmaxf(accA[k] + bb[k], 0.f));
          sB[k] = (short)f2bf(fmaxf(accB[k] + bb[k], 0.f));
        }
        *(short8v*)&A_lds[rA][cbase + l7 * 8] = sA;
        *(short8v*)&A_lds[rB][cbase + l7 * 8] = sB;
      }
    }
  }
  __syncthreads();

  // phase 2: MFMA over K=128
  f32x4 acc2[4][2];
#pragma unroll
  for (int i = 0; i < 4; i++)
#pragma unroll
    for (int j = 0; j < 2; j++) acc2[i][j] = (f32x4){0.f, 0.f, 0.f, 0.f};

#pragma unroll
  for (int k0 = 0; k0 < NHID; k0 += 32) {
    bf16x8 a[4], b[2];
#pragma unroll
    for (int mt = 0; mt < 4; mt++)
      a[mt] = *(const bf16x8*)&A_lds[mt * 16 + l15][k0 + quad * 8];
#pragma unroll
    for (int nt = 0; nt < 2; nt++) {
      int n = wave * 32 + nt * 16 + l15;
      b[nt] = *(const bf16x8*)(WcT + (size_t)n * NHID + k0 + quad * 8);
    }
#pragma unroll
    for (int mt = 0; mt < 4; mt++)
#pragma unroll
      for (int nt = 0; nt < 2; nt++)
        acc2[mt][nt] = __builtin_amdgcn_mfma_f32_16x16x32_bf16(a[mt], b[nt], acc2[mt][nt], 0, 0, 0);
  }
#pragma unroll
  for (int mt = 0; mt < 4; mt++) {
#pragma unroll
    for (int reg = 0; reg < 4; reg++) {
      int gr = row0 + mt * 16 + quad * 4 + reg;
      if (gr < N_NODES) {
#pragma unroll
        for (int nt = 0; nt < 2; nt++) {
          int gc = wave * 32 + nt * 16 + l15;
          Tb[(size_t)gr * NHID + gc] = f2bf(acc2[mt][nt][reg]);
        }
      }
    }
  }
}

// ---------------------------------------------------------------------------
// Gather 2: two half-row passes (pass 0: Tb cols 0-63 -> out_mu; pass 1:
// cols 64-127 -> out_lv). One wave per TWO nodes, 8-oct slots, dual-node
// interleave.
// ---------------------------------------------------------------------------
__launch_bounds__(256)
__global__ void gather2_kernel(const unsigned short* __restrict__ Tb,
                               const int2* __restrict__ offs,
                               const unsigned int* __restrict__ edata,
                               const float* __restrict__ bmu,
                               const float* __restrict__ blv,
                               float* __restrict__ out) {
  int wv = (int)((blockIdx.x * blockDim.x + threadIdx.x) >> 6);
  int gA = wv * 2, gB = wv * 2 + 1;
  if (gA >= N_NODES) return;
  int lane = threadIdx.x & 63;
  int oct = lane >> 3, l7 = lane & 7;
  int jA0 = 0, eA = 0, jB0 = 0, eB = 0;
  { int2 o = offs[gA]; jA0 = o.x + oct; eA = o.y; }
  if (gB < N_NODES) { int2 o = offs[gB]; jB0 = o.x + oct; eB = o.y; }

#pragma unroll
  for (int p = 0; p < 2; p++) {
    const int cbase = p * 64;
    const float* bias = (p == 0) ? bmu : blv;
    float accA[8], accB[8];
#pragma unroll
    for (int k = 0; k < 8; k++) { accA[k] = 0.f; accB[k] = 0.f; }
    int jA = jA0, jB = jB0;
    while (jA + 8 < eA && jB + 8 < eB) {
      unsigned ea0 = edata[jA], ea1 = edata[jA + 8];
      unsigned eb0 = edata[jB], eb1 = edata[jB + 8];
      ushort8v ra0 = *(const ushort8v*)(Tb + (size_t)(ea0 >> 16) * NHID + cbase + l7 * 8);
      ushort8v ra1 = *(const ushort8v*)(Tb + (size_t)(ea1 >> 16) * NHID + cbase + l7 * 8);
      ushort8v rb0 = *(const ushort8v*)(Tb + (size_t)(eb0 >> 16) * NHID + cbase + l7 * 8);
      ushort8v rb1 = *(const ushort8v*)(Tb + (size_t)(eb1 >> 16) * NHID + cbase + l7 * 8);
      float wa0 = bf2f((unsigned short)(ea0 & 0xffffu));
      float wa1 = bf2f((unsigned short)(ea1 & 0xffffu));
      float wb0 = bf2f((unsigned short)(eb0 & 0xffffu));
      float wb1 = bf2f((unsigned short)(eb1 & 0xffffu));
#pragma unroll
      for (int k = 0; k < 8; k++) accA[k] += bf2f(ra0[k]) * wa0;
#pragma unroll
      for (int k = 0; k < 8; k++) accA[k] += bf2f(ra1[k]) * wa1;
#pragma unroll
      for (int k = 0; k < 8; k++) accB[k] += bf2f(rb0[k]) * wb0;
#pragma unroll
      for (int k = 0; k < 8; k++) accB[k] += bf2f(rb1[k]) * wb1;
      jA += 16; jB += 16;
    }
    for (; jA < eA; jA += 8) {
      unsigned ea0 = edata[jA];
      ushort8v ra0 = *(const ushort8v*)(Tb + (size_t)(ea0 >> 16) * NHID + cbase + l7 * 8);
      float wa0 = bf2f((unsigned short)(ea0 & 0xffffu));
#pragma unroll
      for (int k = 0; k < 8; k++) accA[k] += bf2f(ra0[k]) * wa0;
    }
    for (; jB < eB; jB += 8) {
      unsigned eb0 = edata[jB];
      ushort8v rb0 = *(const ushort8v*)(Tb + (size_t)(eb0 >> 16) * NHID + cbase + l7 * 8);
      float wb0 = bf2f((unsigned short)(eb0 & 0xffffu));
#pragma unroll
      for (int k = 0; k < 8; k++) accB[k] += bf2f(rb0[k]) * wb0;
    }
#pragma unroll
    for (int k = 0; k < 8; k++) {
      accA[k] += __shfl_down(accA[k], 32, 64);
      accA[k] += __shfl_down(accA[k], 16, 64);
      accA[k] += __shfl_down(accA[k], 8, 64);
      accB[k] += __shfl_down(accB[k], 32, 64);
      accB[k] += __shfl_down(accB[k], 16, 64);
      accB[k] += __shfl_down(accB[k], 8, 64);
    }
    if (lane < 8) {
      const float* bp = bias + l7 * 8;
      float4 b0 = *(const float4*)bp;
      float4 b1v = *(const float4*)(bp + 4);
      size_t obase = (p == 0) ? 0 : (size_t)N_NODES * LATENT;
      float* op = out + obase + (size_t)gA * LATENT + l7 * 8;
      float4 o0, o1;
      o0.x = accA[0] + b0.x; o0.y = accA[1] + b0.y;
      o0.z = accA[2] + b0.z; o0.w = accA[3] + b0.w;
      o1.x = accA[4] + b1v.x; o1.y = accA[5] + b1v.y;
      o1.z = accA[6] + b1v.z; o1.w = accA[7] + b1v.w;
      *(float4*)op = o0;
      *(float4*)(op + 4) = o1;
      if (gB < N_NODES) {
        float* opB = out + obase + (size_t)gB * LATENT + l7 * 8;
        float4 p0, p1;
        p0.x = accB[0] + b0.x; p0.y = accB[1] + b0.y;
        p0.z = accB[2] + b0.z; p0.w = accB[3] + b0.w;
        p1.x = accB[4] + b1v.x; p1.y = accB[5] + b1v.y;
        p1.z = accB[6] + b1v.z; p1.w = accB[7] + b1v.w;
        *(float4*)opB = p0;
        *(float4*)(opB + 4) = p1;
      }
    }
  }
}

extern "C" void kernel_launch(void* const* d_in, const int* in_sizes, int n_in,
                              void* d_out, int out_size, void* d_ws, size_t ws_size,
                              hipStream_t stream) {
  const float* x   = (const float*)d_in[0];
  const int*   src = (const int*)d_in[1];
  const int*   dst = (const int*)d_in[2];
  const float* ew  = (const float*)d_in[3];
  const float* W1  = (const float*)d_in[4];
  const float* b1  = (const float*)d_in[5];
  const float* Wmu = (const float*)d_in[6];
  const float* bmu = (const float*)d_in[7];
  const float* Wlv = (const float*)d_in[8];
  const float* blv = (const float*)d_in[9];
  float* out = (float*)d_out;

  unsigned short* XWb = (unsigned short*)d_ws;             // 12.8 MB
  unsigned short* Tbb = XWb + (size_t)N_NODES * NHID;      // 12.8 MB
  int2* part = (int2*)(Tbb + (size_t)N_NODES * NHID);      // 7.0 MB
  unsigned int* edata = (unsigned int*)(part + (size_t)NB * CAP);  // 3.5 MB
  int2* offs = (int2*)(edata + (size_t)NB * CAP);          // 401 KB
  int* bcur  = (int*)(offs + 50176);                       // 128 ints
  unsigned short* W1T = (unsigned short*)(bcur + 128);     // 64 KB
  unsigned short* WcT = W1T + 128 * NFEAT;                 // 32 KB

  dim3 blk(256);
  int gemm_grid = (N_NODES + 63) / 64;              // 782
  int wave_grid2 = ((N_NODES + 1) / 2 * 64 + 255) / 256;  // 6250

  prep_w_kernel<<<257, blk, 0, stream>>>(W1, Wmu, Wlv, W1T, WcT, bcur);
  gemm1_kernel<<<gemm_grid, blk, 0, stream>>>(x, W1T, XWb);
  coarse_part_kernel<<<CBLK, dim3(512), 0, stream>>>(src, dst, ew, bcur, part);
  fine_kernel<<<NB, dim3(512), 0, stream>>>(bcur, part, offs, edata);
  g1gemm2_kernel<<<gemm_grid, blk, 0, stream>>>(XWb, offs, edata, b1, WcT, Tbb);
  gather2_kernel<<<wave_grid2, blk, 0, stream>>>(Tbb, offs, edata, bmu, blv, out);
}

// Round 10
// 230.144 us; speedup vs baseline: 1.1462x; 1.1462x over previous
//
#include <hip/hip_runtime.h>
#include <hip/hip_bf16.h>

#define N_NODES 50000
#define N_EDGES 800000
#define NFEAT 256
#define NHID 128
#define LATENT 64
#define NB 98       // coarse buckets: dst >> 9 (512 nodes each; 98*512 = 50176)
#define BSH 9
#define CT 4096     // edges per coarse tile
#define CBLK 196    // ceil(800000/4096)
#define CAP 8960    // per-bucket capacity: mean 8192 + 8.5 sigma (~90)

typedef __attribute__((ext_vector_type(8))) short bf16x8;
typedef __attribute__((ext_vector_type(4))) float f32x4;
typedef __attribute__((ext_vector_type(8))) short short8v;
typedef __attribute__((ext_vector_type(8))) unsigned short ushort8v;

__device__ inline unsigned short f2bf(float f) {
  union { float f; unsigned u; } c; c.f = f;
  unsigned r = (c.u + 0x7FFFu + ((c.u >> 16) & 1u)) >> 16;
  return (unsigned short)r;
}
__device__ inline float bf2f(unsigned short u) {
  union { unsigned u; float f; } c; c.u = ((unsigned)u) << 16;
  return c.f;
}

// ---------------------------------------------------------------------------
// Prep: W1T[n][k]=bf16(W1[k][n]) (128x256); WcT[n][k]=bf16([Wmu|Wlv][k][n])
// (128x128). Block 256 zeroes the bucket cursors.
// ---------------------------------------------------------------------------
__launch_bounds__(256)
__global__ void prep_w_kernel(const float* __restrict__ W1,
                              const float* __restrict__ Wmu,
                              const float* __restrict__ Wlv,
                              unsigned short* __restrict__ W1T,
                              unsigned short* __restrict__ WcT,
                              int* __restrict__ bcur) {
  int b = blockIdx.x;
  int t = threadIdx.x;
  if (b < 128) {
    W1T[b * NFEAT + t] = f2bf(W1[(size_t)t * NHID + b]);
  } else if (b < 256) {
    int n = b - 128;
    if (t < NHID) {
      float v = (n < 64) ? Wmu[(size_t)t * LATENT + n]
                         : Wlv[(size_t)t * LATENT + (n - 64)];
      WcT[n * NHID + t] = f2bf(v);
    }
  } else {
    if (t < 128) bcur[t] = 0;
  }
}

// ---------------------------------------------------------------------------
// GEMM1: XWb[50000][128] = bf16( x @ W1 ). 64-row tile, B direct from W1T.
// ---------------------------------------------------------------------------
__launch_bounds__(256)
__global__ void gemm1_kernel(const float* __restrict__ X,
                             const unsigned short* __restrict__ W1T,
                             unsigned short* __restrict__ XWb) {
  __shared__ short A_lds[64][40];
  const int t = threadIdx.x;
  const int lane = t & 63;
  const int wave = t >> 6;
  const int row0 = blockIdx.x * 64;
  const int l15 = lane & 15, quad = lane >> 4;
  const int srow = t >> 2, skg = t & 3;

  f32x4 acc[4][2];
#pragma unroll
  for (int i = 0; i < 4; i++)
#pragma unroll
    for (int j = 0; j < 2; j++) acc[i][j] = (f32x4){0.f, 0.f, 0.f, 0.f};

  for (int k0 = 0; k0 < NFEAT; k0 += 32) {
    int gr = row0 + srow;
    float4 v0, v1;
    if (gr < N_NODES) {
      const float* p = X + (size_t)gr * NFEAT + k0 + skg * 8;
      v0 = *(const float4*)p;
      v1 = *(const float4*)(p + 4);
    } else {
      v0 = make_float4(0.f, 0.f, 0.f, 0.f);
      v1 = v0;
    }
    short8v s;
    s[0] = f2bf(v0.x); s[1] = f2bf(v0.y); s[2] = f2bf(v0.z); s[3] = f2bf(v0.w);
    s[4] = f2bf(v1.x); s[5] = f2bf(v1.y); s[6] = f2bf(v1.z); s[7] = f2bf(v1.w);
    __syncthreads();
    *(short8v*)&A_lds[srow][skg * 8] = s;
    __syncthreads();

    bf16x8 a[4], b[2];
#pragma unroll
    for (int mt = 0; mt < 4; mt++)
      a[mt] = *(const bf16x8*)&A_lds[mt * 16 + l15][quad * 8];
#pragma unroll
    for (int nt = 0; nt < 2; nt++) {
      int n = wave * 32 + nt * 16 + l15;
      b[nt] = *(const bf16x8*)(W1T + (size_t)n * NFEAT + k0 + quad * 8);
    }
#pragma unroll
    for (int mt = 0; mt < 4; mt++)
#pragma unroll
      for (int nt = 0; nt < 2; nt++)
        acc[mt][nt] = __builtin_amdgcn_mfma_f32_16x16x32_bf16(a[mt], b[nt], acc[mt][nt], 0, 0, 0);
  }
#pragma unroll
  for (int mt = 0; mt < 4; mt++) {
#pragma unroll
    for (int reg = 0; reg < 4; reg++) {
      int gr = row0 + mt * 16 + quad * 4 + reg;
      if (gr < N_NODES) {
#pragma unroll
        for (int nt = 0; nt < 2; nt++) {
          int gc = wave * 32 + nt * 16 + l15;
          XWb[(size_t)gr * NHID + gc] = f2bf(acc[mt][nt][reg]);
        }
      }
    }
  }
}

// ---------------------------------------------------------------------------
// Single-pass coarse partition into capacity-padded buckets.
// ---------------------------------------------------------------------------
__launch_bounds__(512)
__global__ void coarse_part_kernel(const int* __restrict__ src,
                                   const int* __restrict__ dst,
                                   const float* __restrict__ ew,
                                   int* __restrict__ bcur,
                                   int2* __restrict__ part) {
  __shared__ int hist[NB], start[NB], cur[NB], gbase[NB];
  __shared__ int sc[128];
  __shared__ int2 stage[CT];
  int t = threadIdx.x;
  if (t < NB) hist[t] = 0;
  __syncthreads();
  int base = blockIdx.x * CT;
#pragma unroll
  for (int k = 0; k < 8; k++) {
    int e = base + t + k * 512;
    if (e < N_EDGES) atomicAdd(&hist[dst[e] >> BSH], 1);
  }
  __syncthreads();
  int v = (t < NB) ? hist[t] : 0;
  if (t < 128) sc[t] = v;
  __syncthreads();
  int x = v;
  for (int ofs = 1; ofs < 128; ofs <<= 1) {
    int y = (t >= ofs && t < 128) ? sc[t - ofs] : 0;
    __syncthreads();
    if (t < 128) { x += y; sc[t] = x; }
    __syncthreads();
  }
  if (t < NB) {
    int st = x - v;
    start[t] = st;
    cur[t] = st;
    gbase[t] = atomicAdd(&bcur[t], hist[t]);
  }
  __syncthreads();
#pragma unroll
  for (int k = 0; k < 8; k++) {
    int e = base + t + k * 512;
    if (e < N_EDGES) {
      int d = dst[e];
      int b = d >> BSH;
      int lp = atomicAdd(&cur[b], 1);
      stage[lp] = make_int2((src[e] << 16) | d, __float_as_int(ew[e]));
    }
  }
  __syncthreads();
  int nedge = min(CT, N_EDGES - base);
  for (int i = t; i < nedge; i += 512) {
    int2 e = stage[i];
    int b = (e.x & 0xffff) >> BSH;
    part[(size_t)b * CAP + gbase[b] + (i - start[b])] = e;
  }
}

// ---------------------------------------------------------------------------
// Per-bucket fine sort -> offs[n]=(beg,end) + dst-sorted packed edata
// (4B: (src<<16)|bf16(w)).
// ---------------------------------------------------------------------------
__launch_bounds__(512)
__global__ void fine_kernel(const int* __restrict__ bcur,
                            const int2* __restrict__ part,
                            int2* __restrict__ offs,
                            unsigned int* __restrict__ edata) {
  __shared__ int nh[512];
  __shared__ int sc[512];
  int t = threadIdx.x;
  int b = blockIdx.x;
  int base = b * CAP;
  int cnt = bcur[b];
  int nb = b << BSH;
  nh[t] = 0;
  __syncthreads();
  for (int i = t; i < cnt; i += 512) {
    int d = part[base + i].x & 0xffff;
    atomicAdd(&nh[d - nb], 1);
  }
  __syncthreads();
  int v = nh[t];
  sc[t] = v;
  __syncthreads();
  int x = v;
  for (int ofs = 1; ofs < 512; ofs <<= 1) {
    int y = (t >= ofs) ? sc[t - ofs] : 0;
    __syncthreads();
    x += y;
    sc[t] = x;
    __syncthreads();
  }
  int beg = base + (x - v);
  offs[nb + t] = make_int2(beg, beg + v);
  nh[t] = beg;
  __syncthreads();
  for (int i = t; i < cnt; i += 512) {
    int2 e = part[base + i];
    int d = e.x & 0xffff;
    int pos = atomicAdd(&nh[d - nb], 1);
    edata[pos] = (unsigned)(e.x & 0xffff0000) | (unsigned)f2bf(__int_as_float(e.y));
  }
}

// ---------------------------------------------------------------------------
// FUSED gather1 + GEMM2, 512 threads = 8 waves (2x occupancy vs 256).
// Phase 1: wave w gathers rows w*8..w*8+7 as 4 DUAL-ROW iterations
// (quarter-wave per edge, 16 lanes x 16B = 256B row).
// Phase 2: K=128 MFMA; 8 waves x 16-col strips; B direct from WcT.
// ---------------------------------------------------------------------------
__launch_bounds__(512)
__global__ void g1gemm2_kernel(const unsigned short* __restrict__ XWb,
                               const int2* __restrict__ offs,
                               const unsigned int* __restrict__ edata,
                               const float* __restrict__ b1,
                               const unsigned short* __restrict__ WcT,
                               unsigned short* __restrict__ Tb) {
  __shared__ short A_lds[64][136];  // 128 cols + 8 pad
  const int t = threadIdx.x;
  const int lane = t & 63;
  const int wave = t >> 6;  // 0..7
  const int row0 = blockIdx.x * 64;
  const int l15 = lane & 15, quad = lane >> 4;

  float bb[8];
#pragma unroll
  for (int k = 0; k < 8; k++) bb[k] = b1[l15 * 8 + k];

  // phase 1: 4 dual-row iterations -> 8 rows per wave
  for (int rr = 0; rr < 4; rr++) {
    int rA = wave * 8 + rr;
    int rB = rA + 4;
    int gA = row0 + rA, gB = row0 + rB;
    float accA[8], accB[8];
#pragma unroll
    for (int k = 0; k < 8; k++) { accA[k] = 0.f; accB[k] = 0.f; }
    int jA = 0, eA = 0, jB = 0, eB = 0;
    if (gA < N_NODES) { int2 o = offs[gA]; jA = o.x + quad; eA = o.y; }
    if (gB < N_NODES) { int2 o = offs[gB]; jB = o.x + quad; eB = o.y; }
    while (jA + 4 < eA && jB + 4 < eB) {
      unsigned a0 = edata[jA], a1 = edata[jA + 4];
      unsigned b0 = edata[jB], b1e = edata[jB + 4];
      ushort8v ra0 = *(const ushort8v*)(XWb + (size_t)(a0 >> 16) * NHID + l15 * 8);
      ushort8v ra1 = *(const ushort8v*)(XWb + (size_t)(a1 >> 16) * NHID + l15 * 8);
      ushort8v rb0 = *(const ushort8v*)(XWb + (size_t)(b0 >> 16) * NHID + l15 * 8);
      ushort8v rb1 = *(const ushort8v*)(XWb + (size_t)(b1e >> 16) * NHID + l15 * 8);
      float wa0 = bf2f((unsigned short)(a0 & 0xffffu));
      float wa1 = bf2f((unsigned short)(a1 & 0xffffu));
      float wb0 = bf2f((unsigned short)(b0 & 0xffffu));
      float wb1 = bf2f((unsigned short)(b1e & 0xffffu));
#pragma unroll
      for (int k = 0; k < 8; k++) accA[k] += bf2f(ra0[k]) * wa0;
#pragma unroll
      for (int k = 0; k < 8; k++) accA[k] += bf2f(ra1[k]) * wa1;
#pragma unroll
      for (int k = 0; k < 8; k++) accB[k] += bf2f(rb0[k]) * wb0;
#pragma unroll
      for (int k = 0; k < 8; k++) accB[k] += bf2f(rb1[k]) * wb1;
      jA += 8; jB += 8;
    }
    for (; jA + 4 < eA; jA += 8) {
      unsigned a0 = edata[jA], a1 = edata[jA + 4];
      ushort8v ra0 = *(const ushort8v*)(XWb + (size_t)(a0 >> 16) * NHID + l15 * 8);
      ushort8v ra1 = *(const ushort8v*)(XWb + (size_t)(a1 >> 16) * NHID + l15 * 8);
      float wa0 = bf2f((unsigned short)(a0 & 0xffffu));
      float wa1 = bf2f((unsigned short)(a1 & 0xffffu));
#pragma unroll
      for (int k = 0; k < 8; k++) accA[k] += bf2f(ra0[k]) * wa0;
#pragma unroll
      for (int k = 0; k < 8; k++) accA[k] += bf2f(ra1[k]) * wa1;
    }
    if (jA < eA) {
      unsigned a0 = edata[jA];
      ushort8v ra0 = *(const ushort8v*)(XWb + (size_t)(a0 >> 16) * NHID + l15 * 8);
      float wa0 = bf2f((unsigned short)(a0 & 0xffffu));
#pragma unroll
      for (int k = 0; k < 8; k++) accA[k] += bf2f(ra0[k]) * wa0;
    }
    for (; jB + 4 < eB; jB += 8) {
      unsigned b0 = edata[jB], b1e = edata[jB + 4];
      ushort8v rb0 = *(const ushort8v*)(XWb + (size_t)(b0 >> 16) * NHID + l15 * 8);
      ushort8v rb1 = *(const ushort8v*)(XWb + (size_t)(b1e >> 16) * NHID + l15 * 8);
      float wb0 = bf2f((unsigned short)(b0 & 0xffffu));
      float wb1 = bf2f((unsigned short)(b1e & 0xffffu));
#pragma unroll
      for (int k = 0; k < 8; k++) accB[k] += bf2f(rb0[k]) * wb0;
#pragma unroll
      for (int k = 0; k < 8; k++) accB[k] += bf2f(rb1[k]) * wb1;
    }
    if (jB < eB) {
      unsigned b0 = edata[jB];
      ushort8v rb0 = *(const ushort8v*)(XWb + (size_t)(b0 >> 16) * NHID + l15 * 8);
      float wb0 = bf2f((unsigned short)(b0 & 0xffffu));
#pragma unroll
      for (int k = 0; k < 8; k++) accB[k] += bf2f(rb0[k]) * wb0;
    }
#pragma unroll
    for (int k = 0; k < 8; k++) {
      accA[k] += __shfl_down(accA[k], 32, 64);
      accA[k] += __shfl_down(accA[k], 16, 64);
      accB[k] += __shfl_down(accB[k], 32, 64);
      accB[k] += __shfl_down(accB[k], 16, 64);
    }
    if (lane < 16) {
      short8v sA, sB;
#pragma unroll
      for (int k = 0; k < 8; k++) {
        sA[k] = (short)f2bf(fmaxf(accA[k] + bb[k], 0.f));
        sB[k] = (short)f2bf(fmaxf(accB[k] + bb[k], 0.f));
      }
      *(short8v*)&A_lds[rA][l15 * 8] = sA;
      *(short8v*)&A_lds[rB][l15 * 8] = sB;
    }
  }
  __syncthreads();

  // phase 2: MFMA over K=128; wave w owns cols [w*16, w*16+16)
  f32x4 acc2[4];
#pragma unroll
  for (int i = 0; i < 4; i++) acc2[i] = (f32x4){0.f, 0.f, 0.f, 0.f};

#pragma unroll
  for (int k0 = 0; k0 < NHID; k0 += 32) {
    bf16x8 a[4], b;
#pragma unroll
    for (int mt = 0; mt < 4; mt++)
      a[mt] = *(const bf16x8*)&A_lds[mt * 16 + l15][k0 + quad * 8];
    {
      int n = wave * 16 + l15;
      b = *(const bf16x8*)(WcT + (size_t)n * NHID + k0 + quad * 8);
    }
#pragma unroll
    for (int mt = 0; mt < 4; mt++)
      acc2[mt] = __builtin_amdgcn_mfma_f32_16x16x32_bf16(a[mt], b, acc2[mt], 0, 0, 0);
  }
#pragma unroll
  for (int mt = 0; mt < 4; mt++) {
#pragma unroll
    for (int reg = 0; reg < 4; reg++) {
      int gr = row0 + mt * 16 + quad * 4 + reg;
      if (gr < N_NODES) {
        int gc = wave * 16 + l15;
        Tb[(size_t)gr * NHID + gc] = f2bf(acc2[mt][reg]);
      }
    }
  }
}

// ---------------------------------------------------------------------------
// Gather 2: one wave per TWO nodes (interleaved, 2-deep each -> 4 loads in
// flight per quad). out_mu = bmu + sum Tb[src][0:64]*w ; out_lv cols 64:128.
// ---------------------------------------------------------------------------
__launch_bounds__(256)
__global__ void gather2_kernel(const unsigned short* __restrict__ Tb,
                               const int2* __restrict__ offs,
                               const unsigned int* __restrict__ edata,
                               const float* __restrict__ bmu,
                               const float* __restrict__ blv,
                               float* __restrict__ out) {
  int wv = (int)((blockIdx.x * blockDim.x + threadIdx.x) >> 6);
  int gA = wv * 2, gB = wv * 2 + 1;
  if (gA >= N_NODES) return;
  int lane = threadIdx.x & 63;
  int quad = lane >> 4;
  int c8 = lane & 15;
  float accA[8], accB[8];
#pragma unroll
  for (int k = 0; k < 8; k++) { accA[k] = 0.f; accB[k] = 0.f; }
  int jA = 0, eA = 0, jB = 0, eB = 0;
  { int2 o = offs[gA]; jA = o.x + quad; eA = o.y; }
  if (gB < N_NODES) { int2 o = offs[gB]; jB = o.x + quad; eB = o.y; }
  while (jA + 4 < eA && jB + 4 < eB) {
    unsigned a0 = edata[jA], a1 = edata[jA + 4];
    unsigned b0 = edata[jB], b1e = edata[jB + 4];
    ushort8v ra0 = *(const ushort8v*)(Tb + (size_t)(a0 >> 16) * NHID + c8 * 8);
    ushort8v ra1 = *(const ushort8v*)(Tb + (size_t)(a1 >> 16) * NHID + c8 * 8);
    ushort8v rb0 = *(const ushort8v*)(Tb + (size_t)(b0 >> 16) * NHID + c8 * 8);
    ushort8v rb1 = *(const ushort8v*)(Tb + (size_t)(b1e >> 16) * NHID + c8 * 8);
    float wa0 = bf2f((unsigned short)(a0 & 0xffffu));
    float wa1 = bf2f((unsigned short)(a1 & 0xffffu));
    float wb0 = bf2f((unsigned short)(b0 & 0xffffu));
    float wb1 = bf2f((unsigned short)(b1e & 0xffffu));
#pragma unroll
    for (int k = 0; k < 8; k++) accA[k] += bf2f(ra0[k]) * wa0;
#pragma unroll
    for (int k = 0; k < 8; k++) accA[k] += bf2f(ra1[k]) * wa1;
#pragma unroll
    for (int k = 0; k < 8; k++) accB[k] += bf2f(rb0[k]) * wb0;
#pragma unroll
    for (int k = 0; k < 8; k++) accB[k] += bf2f(rb1[k]) * wb1;
    jA += 8; jB += 8;
  }
  for (; jA + 4 < eA; jA += 8) {
    unsigned a0 = edata[jA], a1 = edata[jA + 4];
    ushort8v ra0 = *(const ushort8v*)(Tb + (size_t)(a0 >> 16) * NHID + c8 * 8);
    ushort8v ra1 = *(const ushort8v*)(Tb + (size_t)(a1 >> 16) * NHID + c8 * 8);
    float wa0 = bf2f((unsigned short)(a0 & 0xffffu));
    float wa1 = bf2f((unsigned short)(a1 & 0xffffu));
#pragma unroll
    for (int k = 0; k < 8; k++) accA[k] += bf2f(ra0[k]) * wa0;
#pragma unroll
    for (int k = 0; k < 8; k++) accA[k] += bf2f(ra1[k]) * wa1;
  }
  if (jA < eA) {
    unsigned a0 = edata[jA];
    ushort8v ra0 = *(const ushort8v*)(Tb + (size_t)(a0 >> 16) * NHID + c8 * 8);
    float wa0 = bf2f((unsigned short)(a0 & 0xffffu));
#pragma unroll
    for (int k = 0; k < 8; k++) accA[k] += bf2f(ra0[k]) * wa0;
  }
  for (; jB + 4 < eB; jB += 8) {
    unsigned b0 = edata[jB], b1e = edata[jB + 4];
    ushort8v rb0 = *(const ushort8v*)(Tb + (size_t)(b0 >> 16) * NHID + c8 * 8);
    ushort8v rb1 = *(const ushort8v*)(Tb + (size_t)(b1e >> 16) * NHID + c8 * 8);
    float wb0 = bf2f((unsigned short)(b0 & 0xffffu));
    float wb1 = bf2f((unsigned short)(b1e & 0xffffu));
#pragma unroll
    for (int k = 0; k < 8; k++) accB[k] += bf2f(rb0[k]) * wb0;
#pragma unroll
    for (int k = 0; k < 8; k++) accB[k] += bf2f(rb1[k]) * wb1;
  }
  if (jB < eB) {
    unsigned b0 = edata[jB];
    ushort8v rb0 = *(const ushort8v*)(Tb + (size_t)(b0 >> 16) * NHID + c8 * 8);
    float wb0 = bf2f((unsigned short)(b0 & 0xffffu));
#pragma unroll
    for (int k = 0; k < 8; k++) accB[k] += bf2f(rb0[k]) * wb0;
  }
#pragma unroll
  for (int k = 0; k < 8; k++) {
    accA[k] += __shfl_down(accA[k], 32, 64);
    accA[k] += __shfl_down(accA[k], 16, 64);
    accB[k] += __shfl_down(accB[k], 32, 64);
    accB[k] += __shfl_down(accB[k], 16, 64);
  }
  if (lane < 8) {
    const float* bp = bmu + c8 * 8;
    float4 b0 = *(const float4*)bp;
    float4 b1v = *(const float4*)(bp + 4);
    float* op = out + (size_t)gA * LATENT + c8 * 8;
    float4 o0, o1;
    o0.x = accA[0] + b0.x; o0.y = accA[1] + b0.y;
    o0.z = accA[2] + b0.z; o0.w = accA[3] + b0.w;
    o1.x = accA[4] + b1v.x; o1.y = accA[5] + b1v.y;
    o1.z = accA[6] + b1v.z; o1.w = accA[7] + b1v.w;
    *(float4*)op = o0;
    *(float4*)(op + 4) = o1;
    if (gB < N_NODES) {
      float* opB = out + (size_t)gB * LATENT + c8 * 8;
      float4 p0, p1;
      p0.x = accB[0] + b0.x; p0.y = accB[1] + b0.y;
      p0.z = accB[2] + b0.z; p0.w = accB[3] + b0.w;
      p1.x = accB[4] + b1v.x; p1.y = accB[5] + b1v.y;
      p1.z = accB[6] + b1v.z; p1.w = accB[7] + b1v.w;
      *(float4*)opB = p0;
      *(float4*)(opB + 4) = p1;
    }
  } else if (lane < 16) {
    int c = c8 - 8;
    const float* bp = blv + c * 8;
    float4 b0 = *(const float4*)bp;
    float4 b1v = *(const float4*)(bp + 4);
    float* op = out + (size_t)N_NODES * LATENT + (size_t)gA * LATENT + c * 8;
    float4 o0, o1;
    o0.x = accA[0] + b0.x; o0.y = accA[1] + b0.y;
    o0.z = accA[2] + b0.z; o0.w = accA[3] + b0.w;
    o1.x = accA[4] + b1v.x; o1.y = accA[5] + b1v.y;
    o1.z = accA[6] + b1v.z; o1.w = accA[7] + b1v.w;
    *(float4*)op = o0;
    *(float4*)(op + 4) = o1;
    if (gB < N_NODES) {
      float* opB = out + (size_t)N_NODES * LATENT + (size_t)gB * LATENT + c * 8;
      float4 p0, p1;
      p0.x = accB[0] + b0.x; p0.y = accB[1] + b0.y;
      p0.z = accB[2] + b0.z; p0.w = accB[3] + b0.w;
      p1.x = accB[4] + b1v.x; p1.y = accB[5] + b1v.y;
      p1.z = accB[6] + b1v.z; p1.w = accB[7] + b1v.w;
      *(float4*)opB = p0;
      *(float4*)(opB + 4) = p1;
    }
  }
}

extern "C" void kernel_launch(void* const* d_in, const int* in_sizes, int n_in,
                              void* d_out, int out_size, void* d_ws, size_t ws_size,
                              hipStream_t stream) {
  const float* x   = (const float*)d_in[0];
  const int*   src = (const int*)d_in[1];
  const int*   dst = (const int*)d_in[2];
  const float* ew  = (const float*)d_in[3];
  const float* W1  = (const float*)d_in[4];
  const float* b1  = (const float*)d_in[5];
  const float* Wmu = (const float*)d_in[6];
  const float* bmu = (const float*)d_in[7];
  const float* Wlv = (const float*)d_in[8];
  const float* blv = (const float*)d_in[9];
  float* out = (float*)d_out;

  unsigned short* XWb = (unsigned short*)d_ws;             // 12.8 MB
  unsigned short* Tbb = XWb + (size_t)N_NODES * NHID;      // 12.8 MB
  int2* part = (int2*)(Tbb + (size_t)N_NODES * NHID);      // 7.0 MB
  unsigned int* edata = (unsigned int*)(part + (size_t)NB * CAP);  // 3.5 MB
  int2* offs = (int2*)(edata + (size_t)NB * CAP);          // 401 KB
  int* bcur  = (int*)(offs + 50176);                       // 128 ints
  unsigned short* W1T = (unsigned short*)(bcur + 128);     // 64 KB
  unsigned short* WcT = W1T + 128 * NFEAT;                 // 32 KB

  dim3 blk(256);
  int gemm_grid = (N_NODES + 63) / 64;              // 782
  int wave_grid2 = ((N_NODES + 1) / 2 * 64 + 255) / 256;  // 6250

  prep_w_kernel<<<257, blk, 0, stream>>>(W1, Wmu, Wlv, W1T, WcT, bcur);
  gemm1_kernel<<<gemm_grid, blk, 0, stream>>>(x, W1T, XWb);
  coarse_part_kernel<<<CBLK, dim3(512), 0, stream>>>(src, dst, ew, bcur, part);
  fine_kernel<<<NB, dim3(512), 0, stream>>>(bcur, part, offs, edata);
  g1gemm2_kernel<<<gemm_grid, dim3(512), 0, stream>>>(XWb, offs, edata, b1, WcT, Tbb);
  gather2_kernel<<<wave_grid2, blk, 0, stream>>>(Tbb, offs, edata, bmu, blv, out);
}

// Round 11
// 212.563 us; speedup vs baseline: 1.2410x; 1.0827x over previous
//
#include <hip/hip_runtime.h>
#include <hip/hip_bf16.h>

#define N_NODES 50000
#define N_EDGES 800000
#define NFEAT 256
#define NHID 128
#define LATENT 64
#define NB 196      // coarse buckets: dst >> 8 (256 nodes each; 196*256 = 50176)
#define BSH 8
#define CT 4096     // edges per coarse tile
#define CBLK 196    // ceil(800000/4096)
#define CAP 4608    // per-bucket capacity: mean 4082 + ~8 sigma (~64)
#define GEMM_GRID 782

typedef __attribute__((ext_vector_type(8))) short bf16x8;
typedef __attribute__((ext_vector_type(4))) float f32x4;
typedef __attribute__((ext_vector_type(4))) short short4v;
typedef __attribute__((ext_vector_type(8))) short short8v;
typedef __attribute__((ext_vector_type(8))) unsigned short ushort8v;

__device__ inline unsigned short f2bf(float f) {
  union { float f; unsigned u; } c; c.f = f;
  unsigned r = (c.u + 0x7FFFu + ((c.u >> 16) & 1u)) >> 16;
  return (unsigned short)r;
}
__device__ inline float bf2f(unsigned short u) {
  union { unsigned u; float f; } c; c.u = ((unsigned)u) << 16;
  return c.f;
}

// ---------------------------------------------------------------------------
// Prep: W1T[n][k]=bf16(W1[k][n]) (128x256); WcT[n][k]=bf16([Wmu|Wlv][k][n])
// (128x128). Block 256 zeroes the bucket cursors.
// ---------------------------------------------------------------------------
__launch_bounds__(256)
__global__ void prep_w_kernel(const float* __restrict__ W1,
                              const float* __restrict__ Wmu,
                              const float* __restrict__ Wlv,
                              unsigned short* __restrict__ W1T,
                              unsigned short* __restrict__ WcT,
                              int* __restrict__ bcur) {
  int b = blockIdx.x;
  int t = threadIdx.x;
  if (b < 128) {
    W1T[b * NFEAT + t] = f2bf(W1[(size_t)t * NHID + b]);
  } else if (b < 256) {
    int n = b - 128;
    if (t < NHID) {
      float v = (n < 64) ? Wmu[(size_t)t * LATENT + n]
                         : Wlv[(size_t)t * LATENT + (n - 64)];
      WcT[n * NHID + t] = f2bf(v);
    }
  } else {
    bcur[t] = 0;  // 256 ints cover NB=196
  }
}

// ---------------------------------------------------------------------------
// MERGED: blocks [0,782) = GEMM1 64-row tiles (8 waves x 16-col strips, B
// direct from W1T); blocks [782, 978) = coarse partition tiles. The two jobs
// are independent and stress disjoint pipes -> run concurrently in one
// dispatch instead of serially.
// ---------------------------------------------------------------------------
__launch_bounds__(512)
__global__ void gemm1_coarse_kernel(const float* __restrict__ X,
                                    const unsigned short* __restrict__ W1T,
                                    unsigned short* __restrict__ XWb,
                                    const int* __restrict__ src,
                                    const int* __restrict__ dst,
                                    const float* __restrict__ ew,
                                    int* __restrict__ bcur,
                                    int2* __restrict__ part) {
  __shared__ union U {
    struct { short A[64][40]; } g;                     // 5.1 KB
    struct {
      int hist[NB], start[NB], cur[NB], gbase[NB];     // 3.1 KB
      int sc[256];                                     // 1 KB
      int2 stage[CT];                                  // 32 KB
    } c;
  } u;
  const int t = threadIdx.x;

  if (blockIdx.x < GEMM_GRID) {
    // ----- GEMM1 tile -----
    const int lane = t & 63;
    const int wave = t >> 6;  // 0..7
    const int row0 = blockIdx.x * 64;
    const int l15 = lane & 15, quad = lane >> 4;
    const int srow = t >> 3, skg = t & 7;  // 64 rows x 8 groups of 4 floats

    f32x4 acc[4];
#pragma unroll
    for (int i = 0; i < 4; i++) acc[i] = (f32x4){0.f, 0.f, 0.f, 0.f};

    for (int k0 = 0; k0 < NFEAT; k0 += 32) {
      int gr = row0 + srow;
      float4 v = (gr < N_NODES)
                     ? *(const float4*)(X + (size_t)gr * NFEAT + k0 + skg * 4)
                     : make_float4(0.f, 0.f, 0.f, 0.f);
      short4v s;
      s.x = f2bf(v.x); s.y = f2bf(v.y); s.z = f2bf(v.z); s.w = f2bf(v.w);
      __syncthreads();
      *(short4v*)&u.g.A[srow][skg * 4] = s;
      __syncthreads();

      bf16x8 a[4], b;
#pragma unroll
      for (int mt = 0; mt < 4; mt++)
        a[mt] = *(const bf16x8*)&u.g.A[mt * 16 + l15][quad * 8];
      {
        int n = wave * 16 + l15;
        b = *(const bf16x8*)(W1T + (size_t)n * NFEAT + k0 + quad * 8);
      }
#pragma unroll
      for (int mt = 0; mt < 4; mt++)
        acc[mt] = __builtin_amdgcn_mfma_f32_16x16x32_bf16(a[mt], b, acc[mt], 0, 0, 0);
    }
#pragma unroll
    for (int mt = 0; mt < 4; mt++) {
#pragma unroll
      for (int reg = 0; reg < 4; reg++) {
        int gr = row0 + mt * 16 + quad * 4 + reg;
        if (gr < N_NODES) {
          int gc = wave * 16 + l15;
          XWb[(size_t)gr * NHID + gc] = f2bf(acc[mt][reg]);
        }
      }
    }
  } else {
    // ----- coarse partition tile -----
    int bid = blockIdx.x - GEMM_GRID;
    if (t < NB) u.c.hist[t] = 0;
    __syncthreads();
    int base = bid * CT;
#pragma unroll
    for (int k = 0; k < 8; k++) {
      int e = base + t + k * 512;
      if (e < N_EDGES) atomicAdd(&u.c.hist[dst[e] >> BSH], 1);
    }
    __syncthreads();
    int v = (t < NB) ? u.c.hist[t] : 0;
    if (t < 256) u.c.sc[t] = v;
    __syncthreads();
    int x = v;
    for (int ofs = 1; ofs < 256; ofs <<= 1) {
      int y = (t >= ofs && t < 256) ? u.c.sc[t - ofs] : 0;
      __syncthreads();
      if (t < 256) { x += y; u.c.sc[t] = x; }
      __syncthreads();
    }
    if (t < NB) {
      int st = x - v;
      u.c.start[t] = st;
      u.c.cur[t] = st;
      u.c.gbase[t] = atomicAdd(&bcur[t], u.c.hist[t]);
    }
    __syncthreads();
#pragma unroll
    for (int k = 0; k < 8; k++) {
      int e = base + t + k * 512;
      if (e < N_EDGES) {
        int d = dst[e];
        int b = d >> BSH;
        int lp = atomicAdd(&u.c.cur[b], 1);
        u.c.stage[lp] = make_int2((src[e] << 16) | d, __float_as_int(ew[e]));
      }
    }
    __syncthreads();
    int nedge = min(CT, N_EDGES - base);
    for (int i = t; i < nedge; i += 512) {
      int2 e = u.c.stage[i];
      int b = (e.x & 0xffff) >> BSH;
      part[(size_t)b * CAP + u.c.gbase[b] + (i - u.c.start[b])] = e;
    }
  }
}

// ---------------------------------------------------------------------------
// Per-bucket fine sort (256-node buckets, 196 blocks) -> offs[n]=(beg,end)
// + dst-sorted packed edata (4B: (src<<16)|bf16(w)).
// ---------------------------------------------------------------------------
__launch_bounds__(512)
__global__ void fine_kernel(const int* __restrict__ bcur,
                            const int2* __restrict__ part,
                            int2* __restrict__ offs,
                            unsigned int* __restrict__ edata) {
  __shared__ int nh[256];
  __shared__ int sc[256];
  int t = threadIdx.x;
  int b = blockIdx.x;
  int base = b * CAP;
  int cnt = bcur[b];
  int nb = b << BSH;
  if (t < 256) nh[t] = 0;
  __syncthreads();
  for (int i = t; i < cnt; i += 512) {
    int d = part[base + i].x & 0xffff;
    atomicAdd(&nh[d - nb], 1);
  }
  __syncthreads();
  int v = (t < 256) ? nh[t] : 0;
  if (t < 256) sc[t] = v;
  __syncthreads();
  int x = v;
  for (int ofs = 1; ofs < 256; ofs <<= 1) {
    int y = (t >= ofs && t < 256) ? sc[t - ofs] : 0;
    __syncthreads();
    if (t < 256) { x += y; sc[t] = x; }
    __syncthreads();
  }
  if (t < 256) {
    int beg = base + (x - v);
    offs[nb + t] = make_int2(beg, beg + v);
    nh[t] = beg;
  }
  __syncthreads();
  for (int i = t; i < cnt; i += 512) {
    int2 e = part[base + i];
    int d = e.x & 0xffff;
    int pos = atomicAdd(&nh[d - nb], 1);
    edata[pos] = (unsigned)(e.x & 0xffff0000) | (unsigned)f2bf(__int_as_float(e.y));
  }
}

// ---------------------------------------------------------------------------
// FUSED gather1 + GEMM2 (R8 winner: 256 thr, dual-row interleave).
// Phase 1: wave w gathers rows w*16..w*16+15 as 8 dual-row iterations.
// Phase 2: K=128 MFMA; 4 waves x 32-col strips; B direct from WcT.
// ---------------------------------------------------------------------------
__launch_bounds__(256)
__global__ void g1gemm2_kernel(const unsigned short* __restrict__ XWb,
                               const int2* __restrict__ offs,
                               const unsigned int* __restrict__ edata,
                               const float* __restrict__ b1,
                               const unsigned short* __restrict__ WcT,
                               unsigned short* __restrict__ Tb) {
  __shared__ short A_lds[64][136];  // 128 cols + 8 pad
  const int t = threadIdx.x;
  const int lane = t & 63;
  const int wave = t >> 6;
  const int row0 = blockIdx.x * 64;
  const int l15 = lane & 15, quad = lane >> 4;

  float bb[8];
#pragma unroll
  for (int k = 0; k < 8; k++) bb[k] = b1[l15 * 8 + k];

  for (int rr = 0; rr < 8; rr++) {
    int rA = wave * 16 + rr;
    int rB = rA + 8;
    int gA = row0 + rA, gB = row0 + rB;
    float accA[8], accB[8];
#pragma unroll
    for (int k = 0; k < 8; k++) { accA[k] = 0.f; accB[k] = 0.f; }
    int jA = 0, eA = 0, jB = 0, eB = 0;
    if (gA < N_NODES) { int2 o = offs[gA]; jA = o.x + quad; eA = o.y; }
    if (gB < N_NODES) { int2 o = offs[gB]; jB = o.x + quad; eB = o.y; }
    while (jA + 4 < eA && jB + 4 < eB) {
      unsigned a0 = edata[jA], a1 = edata[jA + 4];
      unsigned b0 = edata[jB], b1e = edata[jB + 4];
      ushort8v ra0 = *(const ushort8v*)(XWb + (size_t)(a0 >> 16) * NHID + l15 * 8);
      ushort8v ra1 = *(const ushort8v*)(XWb + (size_t)(a1 >> 16) * NHID + l15 * 8);
      ushort8v rb0 = *(const ushort8v*)(XWb + (size_t)(b0 >> 16) * NHID + l15 * 8);
      ushort8v rb1 = *(const ushort8v*)(XWb + (size_t)(b1e >> 16) * NHID + l15 * 8);
      float wa0 = bf2f((unsigned short)(a0 & 0xffffu));
      float wa1 = bf2f((unsigned short)(a1 & 0xffffu));
      float wb0 = bf2f((unsigned short)(b0 & 0xffffu));
      float wb1 = bf2f((unsigned short)(b1e & 0xffffu));
#pragma unroll
      for (int k = 0; k < 8; k++) accA[k] += bf2f(ra0[k]) * wa0;
#pragma unroll
      for (int k = 0; k < 8; k++) accA[k] += bf2f(ra1[k]) * wa1;
#pragma unroll
      for (int k = 0; k < 8; k++) accB[k] += bf2f(rb0[k]) * wb0;
#pragma unroll
      for (int k = 0; k < 8; k++) accB[k] += bf2f(rb1[k]) * wb1;
      jA += 8; jB += 8;
    }
    for (; jA + 4 < eA; jA += 8) {
      unsigned a0 = edata[jA], a1 = edata[jA + 4];
      ushort8v ra0 = *(const ushort8v*)(XWb + (size_t)(a0 >> 16) * NHID + l15 * 8);
      ushort8v ra1 = *(const ushort8v*)(XWb + (size_t)(a1 >> 16) * NHID + l15 * 8);
      float wa0 = bf2f((unsigned short)(a0 & 0xffffu));
      float wa1 = bf2f((unsigned short)(a1 & 0xffffu));
#pragma unroll
      for (int k = 0; k < 8; k++) accA[k] += bf2f(ra0[k]) * wa0;
#pragma unroll
      for (int k = 0; k < 8; k++) accA[k] += bf2f(ra1[k]) * wa1;
    }
    if (jA < eA) {
      unsigned a0 = edata[jA];
      ushort8v ra0 = *(const ushort8v*)(XWb + (size_t)(a0 >> 16) * NHID + l15 * 8);
      float wa0 = bf2f((unsigned short)(a0 & 0xffffu));
#pragma unroll
      for (int k = 0; k < 8; k++) accA[k] += bf2f(ra0[k]) * wa0;
    }
    for (; jB + 4 < eB; jB += 8) {
      unsigned b0 = edata[jB], b1e = edata[jB + 4];
      ushort8v rb0 = *(const ushort8v*)(XWb + (size_t)(b0 >> 16) * NHID + l15 * 8);
      ushort8v rb1 = *(const ushort8v*)(XWb + (size_t)(b1e >> 16) * NHID + l15 * 8);
      float wb0 = bf2f((unsigned short)(b0 & 0xffffu));
      float wb1 = bf2f((unsigned short)(b1e & 0xffffu));
#pragma unroll
      for (int k = 0; k < 8; k++) accB[k] += bf2f(rb0[k]) * wb0;
#pragma unroll
      for (int k = 0; k < 8; k++) accB[k] += bf2f(rb1[k]) * wb1;
    }
    if (jB < eB) {
      unsigned b0 = edata[jB];
      ushort8v rb0 = *(const ushort8v*)(XWb + (size_t)(b0 >> 16) * NHID + l15 * 8);
      float wb0 = bf2f((unsigned short)(b0 & 0xffffu));
#pragma unroll
      for (int k = 0; k < 8; k++) accB[k] += bf2f(rb0[k]) * wb0;
    }
#pragma unroll
    for (int k = 0; k < 8; k++) {
      accA[k] += __shfl_down(accA[k], 32, 64);
      accA[k] += __shfl_down(accA[k], 16, 64);
      accB[k] += __shfl_down(accB[k], 32, 64);
      accB[k] += __shfl_down(accB[k], 16, 64);
    }
    if (lane < 16) {
      short8v sA, sB;
#pragma unroll
      for (int k = 0; k < 8; k++) {
        sA[k] = (short)f2bf(fmaxf(accA[k] + bb[k], 0.f));
        sB[k] = (short)f2bf(fmaxf(accB[k] + bb[k], 0.f));
      }
      *(short8v*)&A_lds[rA][l15 * 8] = sA;
      *(short8v*)&A_lds[rB][l15 * 8] = sB;
    }
  }
  __syncthreads();

  f32x4 acc2[4][2];
#pragma unroll
  for (int i = 0; i < 4; i++)
#pragma unroll
    for (int j = 0; j < 2; j++) acc2[i][j] = (f32x4){0.f, 0.f, 0.f, 0.f};

#pragma unroll
  for (int k0 = 0; k0 < NHID; k0 += 32) {
    bf16x8 a[4], b[2];
#pragma unroll
    for (int mt = 0; mt < 4; mt++)
      a[mt] = *(const bf16x8*)&A_lds[mt * 16 + l15][k0 + quad * 8];
#pragma unroll
    for (int nt = 0; nt < 2; nt++) {
      int n = wave * 32 + nt * 16 + l15;
      b[nt] = *(const bf16x8*)(WcT + (size_t)n * NHID + k0 + quad * 8);
    }
#pragma unroll
    for (int mt = 0; mt < 4; mt++)
#pragma unroll
      for (int nt = 0; nt < 2; nt++)
        acc2[mt][nt] = __builtin_amdgcn_mfma_f32_16x16x32_bf16(a[mt], b[nt], acc2[mt][nt], 0, 0, 0);
  }
#pragma unroll
  for (int mt = 0; mt < 4; mt++) {
#pragma unroll
    for (int reg = 0; reg < 4; reg++) {
      int gr = row0 + mt * 16 + quad * 4 + reg;
      if (gr < N_NODES) {
#pragma unroll
        for (int nt = 0; nt < 2; nt++) {
          int gc = wave * 32 + nt * 16 + l15;
          Tb[(size_t)gr * NHID + gc] = f2bf(acc2[mt][nt][reg]);
        }
      }
    }
  }
}

// ---------------------------------------------------------------------------
// Gather 2 (R8 winner): one wave per TWO nodes, dual-node interleave.
// out_mu = bmu + sum Tb[src][0:64]*w ; out_lv cols 64:128.
// ---------------------------------------------------------------------------
__launch_bounds__(256)
__global__ void gather2_kernel(const unsigned short* __restrict__ Tb,
                               const int2* __restrict__ offs,
                               const unsigned int* __restrict__ edata,
                               const float* __restrict__ bmu,
                               const float* __restrict__ blv,
                               float* __restrict__ out) {
  int wv = (int)((blockIdx.x * blockDim.x + threadIdx.x) >> 6);
  int gA = wv * 2, gB = wv * 2 + 1;
  if (gA >= N_NODES) return;
  int lane = threadIdx.x & 63;
  int quad = lane >> 4;
  int c8 = lane & 15;
  float accA[8], accB[8];
#pragma unroll
  for (int k = 0; k < 8; k++) { accA[k] = 0.f; accB[k] = 0.f; }
  int jA = 0, eA = 0, jB = 0, eB = 0;
  { int2 o = offs[gA]; jA = o.x + quad; eA = o.y; }
  if (gB < N_NODES) { int2 o = offs[gB]; jB = o.x + quad; eB = o.y; }
  while (jA + 4 < eA && jB + 4 < eB) {
    unsigned a0 = edata[jA], a1 = edata[jA + 4];
    unsigned b0 = edata[jB], b1e = edata[jB + 4];
    ushort8v ra0 = *(const ushort8v*)(Tb + (size_t)(a0 >> 16) * NHID + c8 * 8);
    ushort8v ra1 = *(const ushort8v*)(Tb + (size_t)(a1 >> 16) * NHID + c8 * 8);
    ushort8v rb0 = *(const ushort8v*)(Tb + (size_t)(b0 >> 16) * NHID + c8 * 8);
    ushort8v rb1 = *(const ushort8v*)(Tb + (size_t)(b1e >> 16) * NHID + c8 * 8);
    float wa0 = bf2f((unsigned short)(a0 & 0xffffu));
    float wa1 = bf2f((unsigned short)(a1 & 0xffffu));
    float wb0 = bf2f((unsigned short)(b0 & 0xffffu));
    float wb1 = bf2f((unsigned short)(b1e & 0xffffu));
#pragma unroll
    for (int k = 0; k < 8; k++) accA[k] += bf2f(ra0[k]) * wa0;
#pragma unroll
    for (int k = 0; k < 8; k++) accA[k] += bf2f(ra1[k]) * wa1;
#pragma unroll
    for (int k = 0; k < 8; k++) accB[k] += bf2f(rb0[k]) * wb0;
#pragma unroll
    for (int k = 0; k < 8; k++) accB[k] += bf2f(rb1[k]) * wb1;
    jA += 8; jB += 8;
  }
  for (; jA + 4 < eA; jA += 8) {
    unsigned a0 = edata[jA], a1 = edata[jA + 4];
    ushort8v ra0 = *(const ushort8v*)(Tb + (size_t)(a0 >> 16) * NHID + c8 * 8);
    ushort8v ra1 = *(const ushort8v*)(Tb + (size_t)(a1 >> 16) * NHID + c8 * 8);
    float wa0 = bf2f((unsigned short)(a0 & 0xffffu));
    float wa1 = bf2f((unsigned short)(a1 & 0xffffu));
#pragma unroll
    for (int k = 0; k < 8; k++) accA[k] += bf2f(ra0[k]) * wa0;
#pragma unroll
    for (int k = 0; k < 8; k++) accA[k] += bf2f(ra1[k]) * wa1;
  }
  if (jA < eA) {
    unsigned a0 = edata[jA];
    ushort8v ra0 = *(const ushort8v*)(Tb + (size_t)(a0 >> 16) * NHID + c8 * 8);
    float wa0 = bf2f((unsigned short)(a0 & 0xffffu));
#pragma unroll
    for (int k = 0; k < 8; k++) accA[k] += bf2f(ra0[k]) * wa0;
  }
  for (; jB + 4 < eB; jB += 8) {
    unsigned b0 = edata[jB], b1e = edata[jB + 4];
    ushort8v rb0 = *(const ushort8v*)(Tb + (size_t)(b0 >> 16) * NHID + c8 * 8);
    ushort8v rb1 = *(const ushort8v*)(Tb + (size_t)(b1e >> 16) * NHID + c8 * 8);
    float wb0 = bf2f((unsigned short)(b0 & 0xffffu));
    float wb1 = bf2f((unsigned short)(b1e & 0xffffu));
#pragma unroll
    for (int k = 0; k < 8; k++) accB[k] += bf2f(rb0[k]) * wb0;
#pragma unroll
    for (int k = 0; k < 8; k++) accB[k] += bf2f(rb1[k]) * wb1;
  }
  if (jB < eB) {
    unsigned b0 = edata[jB];
    ushort8v rb0 = *(const ushort8v*)(Tb + (size_t)(b0 >> 16) * NHID + c8 * 8);
    float wb0 = bf2f((unsigned short)(b0 & 0xffffu));
#pragma unroll
    for (int k = 0; k < 8; k++) accB[k] += bf2f(rb0[k]) * wb0;
  }
#pragma unroll
  for (int k = 0; k < 8; k++) {
    accA[k] += __shfl_down(accA[k], 32, 64);
    accA[k] += __shfl_down(accA[k], 16, 64);
    accB[k] += __shfl_down(accB[k], 32, 64);
    accB[k] += __shfl_down(accB[k], 16, 64);
  }
  if (lane < 8) {
    const float* bp = bmu + c8 * 8;
    float4 b0 = *(const float4*)bp;
    float4 b1v = *(const float4*)(bp + 4);
    float* op = out + (size_t)gA * LATENT + c8 * 8;
    float4 o0, o1;
    o0.x = accA[0] + b0.x; o0.y = accA[1] + b0.y;
    o0.z = accA[2] + b0.z; o0.w = accA[3] + b0.w;
    o1.x = accA[4] + b1v.x; o1.y = accA[5] + b1v.y;
    o1.z = accA[6] + b1v.z; o1.w = accA[7] + b1v.w;
    *(float4*)op = o0;
    *(float4*)(op + 4) = o1;
    if (gB < N_NODES) {
      float* opB = out + (size_t)gB * LATENT + c8 * 8;
      float4 p0, p1;
      p0.x = accB[0] + b0.x; p0.y = accB[1] + b0.y;
      p0.z = accB[2] + b0.z; p0.w = accB[3] + b0.w;
      p1.x = accB[4] + b1v.x; p1.y = accB[5] + b1v.y;
      p1.z = accB[6] + b1v.z; p1.w = accB[7] + b1v.w;
      *(float4*)opB = p0;
      *(float4*)(opB + 4) = p1;
    }
  } else if (lane < 16) {
    int c = c8 - 8;
    const float* bp = blv + c * 8;
    float4 b0 = *(const float4*)bp;
    float4 b1v = *(const float4*)(bp + 4);
    float* op = out + (size_t)N_NODES * LATENT + (size_t)gA * LATENT + c * 8;
    float4 o0, o1;
    o0.x = accA[0] + b0.x; o0.y = accA[1] + b0.y;
    o0.z = accA[2] + b0.z; o0.w = accA[3] + b0.w;
    o1.x = accA[4] + b1v.x; o1.y = accA[5] + b1v.y;
    o1.z = accA[6] + b1v.z; o1.w = accA[7] + b1v.w;
    *(float4*)op = o0;
    *(float4*)(op + 4) = o1;
    if (gB < N_NODES) {
      float* opB = out + (size_t)N_NODES * LATENT + (size_t)gB * LATENT + c * 8;
      float4 p0, p1;
      p0.x = accB[0] + b0.x; p0.y = accB[1] + b0.y;
      p0.z = accB[2] + b0.z; p0.w = accB[3] + b0.w;
      p1.x = accB[4] + b1v.x; p1.y = accB[5] + b1v.y;
      p1.z = accB[6] + b1v.z; p1.w = accB[7] + b1v.w;
      *(float4*)opB = p0;
      *(float4*)(opB + 4) = p1;
    }
  }
}

extern "C" void kernel_launch(void* const* d_in, const int* in_sizes, int n_in,
                              void* d_out, int out_size, void* d_ws, size_t ws_size,
                              hipStream_t stream) {
  const float* x   = (const float*)d_in[0];
  const int*   src = (const int*)d_in[1];
  const int*   dst = (const int*)d_in[2];
  const float* ew  = (const float*)d_in[3];
  const float* W1  = (const float*)d_in[4];
  const float* b1  = (const float*)d_in[5];
  const float* Wmu = (const float*)d_in[6];
  const float* bmu = (const float*)d_in[7];
  const float* Wlv = (const float*)d_in[8];
  const float* blv = (const float*)d_in[9];
  float* out = (float*)d_out;

  unsigned short* XWb = (unsigned short*)d_ws;             // 12.8 MB
  unsigned short* Tbb = XWb + (size_t)N_NODES * NHID;      // 12.8 MB
  int2* part = (int2*)(Tbb + (size_t)N_NODES * NHID);      // 196*4608*8 = 7.2 MB
  unsigned int* edata = (unsigned int*)(part + (size_t)NB * CAP);  // 3.6 MB
  int2* offs = (int2*)(edata + (size_t)NB * CAP);          // 50176*8 = 401 KB
  int* bcur  = (int*)(offs + 50176);                       // 256 ints
  unsigned short* W1T = (unsigned short*)(bcur + 256);     // 64 KB
  unsigned short* WcT = W1T + 128 * NFEAT;                 // 32 KB

  dim3 blk(256);
  int wave_grid2 = ((N_NODES + 1) / 2 * 64 + 255) / 256;  // 6250

  prep_w_kernel<<<257, blk, 0, stream>>>(W1, Wmu, Wlv, W1T, WcT, bcur);
  gemm1_coarse_kernel<<<GEMM_GRID + CBLK, dim3(512), 0, stream>>>(
      x, W1T, XWb, src, dst, ew, bcur, part);
  fine_kernel<<<NB, dim3(512), 0, stream>>>(bcur, part, offs, edata);
  g1gemm2_kernel<<<GEMM_GRID, blk, 0, stream>>>(XWb, offs, edata, b1, WcT, Tbb);
  gather2_kernel<<<wave_grid2, blk, 0, stream>>>(Tbb, offs, edata, bmu, blv, out);
}

// Round 13
// 212.194 us; speedup vs baseline: 1.2432x; 1.0017x over previous
//
#include <hip/hip_runtime.h>
#include <hip/hip_bf16.h>

#define N_NODES 50000
#define N_EDGES 800000
#define NFEAT 256
#define NHID 128
#define LATENT 64
#define NB 196      // coarse buckets: dst >> 8 (256 nodes each; 196*256 = 50176)
#define BSH 8
#define CT 4096     // edges per coarse tile
#define CBLK 196    // ceil(800000/4096)
#define CAP 4608    // per-bucket capacity: mean 4082 + ~8 sigma
#define GEMM_GRID 782

typedef __attribute__((ext_vector_type(8))) short bf16x8;
typedef __attribute__((ext_vector_type(4))) float f32x4;
typedef __attribute__((ext_vector_type(4))) short short4v;
typedef __attribute__((ext_vector_type(8))) short short8v;
typedef __attribute__((ext_vector_type(8))) unsigned short ushort8v;

__device__ inline unsigned short f2bf(float f) {
  union { float f; unsigned u; } c; c.f = f;
  unsigned r = (c.u + 0x7FFFu + ((c.u >> 16) & 1u)) >> 16;
  return (unsigned short)r;
}
__device__ inline float bf2f(unsigned short u) {
  union { unsigned u; float f; } c; c.u = ((unsigned)u) << 16;
  return c.f;
}

// ---------------------------------------------------------------------------
// Prep: W1T[n][k]=bf16(W1[k][n]) (128x256); WcT[n][k]=bf16([Wmu|Wlv][k][n])
// (128x128). Block 256 zeroes the bucket cursors.
// ---------------------------------------------------------------------------
__launch_bounds__(256)
__global__ void prep_w_kernel(const float* __restrict__ W1,
                              const float* __restrict__ Wmu,
                              const float* __restrict__ Wlv,
                              unsigned short* __restrict__ W1T,
                              unsigned short* __restrict__ WcT,
                              int* __restrict__ bcur) {
  int b = blockIdx.x;
  int t = threadIdx.x;
  if (b < 128) {
    W1T[b * NFEAT + t] = f2bf(W1[(size_t)t * NHID + b]);
  } else if (b < 256) {
    int n = b - 128;
    if (t < NHID) {
      float v = (n < 64) ? Wmu[(size_t)t * LATENT + n]
                         : Wlv[(size_t)t * LATENT + (n - 64)];
      WcT[n * NHID + t] = f2bf(v);
    }
  } else {
    bcur[t] = 0;  // 256 ints cover NB=196
  }
}

// ---------------------------------------------------------------------------
// MERGED: blocks [0,782) = GEMM1 64-row tiles (8 waves x 16-col strips, B
// direct from W1T); blocks [782, 978) = coarse partition tiles. The two jobs
// are independent and stress disjoint pipes -> run concurrently in one
// dispatch instead of serially.
// ---------------------------------------------------------------------------
__launch_bounds__(512)
__global__ void gemm1_coarse_kernel(const float* __restrict__ X,
                                    const unsigned short* __restrict__ W1T,
                                    unsigned short* __restrict__ XWb,
                                    const int* __restrict__ src,
                                    const int* __restrict__ dst,
                                    const float* __restrict__ ew,
                                    int* __restrict__ bcur,
                                    int2* __restrict__ part) {
  __shared__ union U {
    struct { short A[64][40]; } g;                     // 5.1 KB
    struct {
      int hist[NB], start[NB], cur[NB], gbase[NB];     // 3.1 KB
      int sc[256];                                     // 1 KB
      int2 stage[CT];                                  // 32 KB
    } c;
  } u;
  const int t = threadIdx.x;

  if (blockIdx.x < GEMM_GRID) {
    // ----- GEMM1 tile -----
    const int lane = t & 63;
    const int wave = t >> 6;  // 0..7
    const int row0 = blockIdx.x * 64;
    const int l15 = lane & 15, quad = lane >> 4;
    const int srow = t >> 3, skg = t & 7;  // 64 rows x 8 groups of 4 floats

    f32x4 acc[4];
#pragma unroll
    for (int i = 0; i < 4; i++) acc[i] = (f32x4){0.f, 0.f, 0.f, 0.f};

    for (int k0 = 0; k0 < NFEAT; k0 += 32) {
      int gr = row0 + srow;
      float4 v = (gr < N_NODES)
                     ? *(const float4*)(X + (size_t)gr * NFEAT + k0 + skg * 4)
                     : make_float4(0.f, 0.f, 0.f, 0.f);
      short4v s;
      s.x = f2bf(v.x); s.y = f2bf(v.y); s.z = f2bf(v.z); s.w = f2bf(v.w);
      __syncthreads();
      *(short4v*)&u.g.A[srow][skg * 4] = s;
      __syncthreads();

      bf16x8 a[4], b;
#pragma unroll
      for (int mt = 0; mt < 4; mt++)
        a[mt] = *(const bf16x8*)&u.g.A[mt * 16 + l15][quad * 8];
      {
        int n = wave * 16 + l15;
        b = *(const bf16x8*)(W1T + (size_t)n * NFEAT + k0 + quad * 8);
      }
#pragma unroll
      for (int mt = 0; mt < 4; mt++)
        acc[mt] = __builtin_amdgcn_mfma_f32_16x16x32_bf16(a[mt], b, acc[mt], 0, 0, 0);
    }
#pragma unroll
    for (int mt = 0; mt < 4; mt++) {
#pragma unroll
      for (int reg = 0; reg < 4; reg++) {
        int gr = row0 + mt * 16 + quad * 4 + reg;
        if (gr < N_NODES) {
          int gc = wave * 16 + l15;
          XWb[(size_t)gr * NHID + gc] = f2bf(acc[mt][reg]);
        }
      }
    }
  } else {
    // ----- coarse partition tile -----
    int bid = blockIdx.x - GEMM_GRID;
    if (t < NB) u.c.hist[t] = 0;
    __syncthreads();
    int base = bid * CT;
#pragma unroll
    for (int k = 0; k < 8; k++) {
      int e = base + t + k * 512;
      if (e < N_EDGES) atomicAdd(&u.c.hist[dst[e] >> BSH], 1);
    }
    __syncthreads();
    int v = (t < NB) ? u.c.hist[t] : 0;
    if (t < 256) u.c.sc[t] = v;
    __syncthreads();
    int x = v;
    for (int ofs = 1; ofs < 256; ofs <<= 1) {
      int y = (t >= ofs && t < 256) ? u.c.sc[t - ofs] : 0;
      __syncthreads();
      if (t < 256) { x += y; u.c.sc[t] = x; }
      __syncthreads();
    }
    if (t < NB) {
      int st = x - v;
      u.c.start[t] = st;
      u.c.cur[t] = st;
      u.c.gbase[t] = atomicAdd(&bcur[t], u.c.hist[t]);
    }
    __syncthreads();
#pragma unroll
    for (int k = 0; k < 8; k++) {
      int e = base + t + k * 512;
      if (e < N_EDGES) {
        int d = dst[e];
        int b = d >> BSH;
        int lp = atomicAdd(&u.c.cur[b], 1);
        u.c.stage[lp] = make_int2((src[e] << 16) | d, __float_as_int(ew[e]));
      }
    }
    __syncthreads();
    int nedge = min(CT, N_EDGES - base);
    for (int i = t; i < nedge; i += 512) {
      int2 e = u.c.stage[i];
      int b = (e.x & 0xffff) >> BSH;
      part[(size_t)b * CAP + u.c.gbase[b] + (i - u.c.start[b])] = e;
    }
  }
}

// ---------------------------------------------------------------------------
// Per-bucket fine sort (256-node buckets, 196 blocks) -> offs[n]=(beg,end)
// + dst-sorted packed edata (4B: (src<<16)|bf16(w)).
// ---------------------------------------------------------------------------
__launch_bounds__(512)
__global__ void fine_kernel(const int* __restrict__ bcur,
                            const int2* __restrict__ part,
                            int2* __restrict__ offs,
                            unsigned int* __restrict__ edata) {
  __shared__ int nh[256];
  __shared__ int sc[256];
  int t = threadIdx.x;
  int b = blockIdx.x;
  int base = b * CAP;
  int cnt = bcur[b];
  int nb = b << BSH;
  if (t < 256) nh[t] = 0;
  __syncthreads();
  for (int i = t; i < cnt; i += 512) {
    int d = part[base + i].x & 0xffff;
    atomicAdd(&nh[d - nb], 1);
  }
  __syncthreads();
  int v = (t < 256) ? nh[t] : 0;
  if (t < 256) sc[t] = v;
  __syncthreads();
  int x = v;
  for (int ofs = 1; ofs < 256; ofs <<= 1) {
    int y = (t >= ofs && t < 256) ? sc[t - ofs] : 0;
    __syncthreads();
    if (t < 256) { x += y; sc[t] = x; }
    __syncthreads();
  }
  if (t < 256) {
    int beg = base + (x - v);
    offs[nb + t] = make_int2(beg, beg + v);
    nh[t] = beg;
  }
  __syncthreads();
  for (int i = t; i < cnt; i += 512) {
    int2 e = part[base + i];
    int d = e.x & 0xffff;
    int pos = atomicAdd(&nh[d - nb], 1);
    edata[pos] = (unsigned)(e.x & 0xffff0000) | (unsigned)f2bf(__int_as_float(e.y));
  }
}

// ---------------------------------------------------------------------------
// FUSED gather1 + GEMM2 (256 thr, dual-row interleave).
// Phase 1: wave w gathers rows w*16..w*16+15 as 8 dual-row iterations.
// Phase 2: K=128 MFMA; 4 waves x 32-col strips; B direct from WcT.
// ---------------------------------------------------------------------------
__launch_bounds__(256)
__global__ void g1gemm2_kernel(const unsigned short* __restrict__ XWb,
                               const int2* __restrict__ offs,
                               const unsigned int* __restrict__ edata,
                               const float* __restrict__ b1,
                               const unsigned short* __restrict__ WcT,
                               unsigned short* __restrict__ Tb) {
  __shared__ short A_lds[64][136];  // 128 cols + 8 pad
  const int t = threadIdx.x;
  const int lane = t & 63;
  const int wave = t >> 6;
  const int row0 = blockIdx.x * 64;
  const int l15 = lane & 15, quad = lane >> 4;

  float bb[8];
#pragma unroll
  for (int k = 0; k < 8; k++) bb[k] = b1[l15 * 8 + k];

  for (int rr = 0; rr < 8; rr++) {
    int rA = wave * 16 + rr;
    int rB = rA + 8;
    int gA = row0 + rA, gB = row0 + rB;
    float accA[8], accB[8];
#pragma unroll
    for (int k = 0; k < 8; k++) { accA[k] = 0.f; accB[k] = 0.f; }
    int jA = 0, eA = 0, jB = 0, eB = 0;
    if (gA < N_NODES) { int2 o = offs[gA]; jA = o.x + quad; eA = o.y; }
    if (gB < N_NODES) { int2 o = offs[gB]; jB = o.x + quad; eB = o.y; }
    while (jA + 4 < eA && jB + 4 < eB) {
      unsigned a0 = edata[jA], a1 = edata[jA + 4];
      unsigned b0 = edata[jB], b1e = edata[jB + 4];
      ushort8v ra0 = *(const ushort8v*)(XWb + (size_t)(a0 >> 16) * NHID + l15 * 8);
      ushort8v ra1 = *(const ushort8v*)(XWb + (size_t)(a1 >> 16) * NHID + l15 * 8);
      ushort8v rb0 = *(const ushort8v*)(XWb + (size_t)(b0 >> 16) * NHID + l15 * 8);
      ushort8v rb1 = *(const ushort8v*)(XWb + (size_t)(b1e >> 16) * NHID + l15 * 8);
      float wa0 = bf2f((unsigned short)(a0 & 0xffffu));
      float wa1 = bf2f((unsigned short)(a1 & 0xffffu));
      float wb0 = bf2f((unsigned short)(b0 & 0xffffu));
      float wb1 = bf2f((unsigned short)(b1e & 0xffffu));
#pragma unroll
      for (int k = 0; k < 8; k++) accA[k] += bf2f(ra0[k]) * wa0;
#pragma unroll
      for (int k = 0; k < 8; k++) accA[k] += bf2f(ra1[k]) * wa1;
#pragma unroll
      for (int k = 0; k < 8; k++) accB[k] += bf2f(rb0[k]) * wb0;
#pragma unroll
      for (int k = 0; k < 8; k++) accB[k] += bf2f(rb1[k]) * wb1;
      jA += 8; jB += 8;
    }
    for (; jA + 4 < eA; jA += 8) {
      unsigned a0 = edata[jA], a1 = edata[jA + 4];
      ushort8v ra0 = *(const ushort8v*)(XWb + (size_t)(a0 >> 16) * NHID + l15 * 8);
      ushort8v ra1 = *(const ushort8v*)(XWb + (size_t)(a1 >> 16) * NHID + l15 * 8);
      float wa0 = bf2f((unsigned short)(a0 & 0xffffu));
      float wa1 = bf2f((unsigned short)(a1 & 0xffffu));
#pragma unroll
      for (int k = 0; k < 8; k++) accA[k] += bf2f(ra0[k]) * wa0;
#pragma unroll
      for (int k = 0; k < 8; k++) accA[k] += bf2f(ra1[k]) * wa1;
    }
    if (jA < eA) {
      unsigned a0 = edata[jA];
      ushort8v ra0 = *(const ushort8v*)(XWb + (size_t)(a0 >> 16) * NHID + l15 * 8);
      float wa0 = bf2f((unsigned short)(a0 & 0xffffu));
#pragma unroll
      for (int k = 0; k < 8; k++) accA[k] += bf2f(ra0[k]) * wa0;
    }
    for (; jB + 4 < eB; jB += 8) {
      unsigned b0 = edata[jB], b1e = edata[jB + 4];
      ushort8v rb0 = *(const ushort8v*)(XWb + (size_t)(b0 >> 16) * NHID + l15 * 8);
      ushort8v rb1 = *(const ushort8v*)(XWb + (size_t)(b1e >> 16) * NHID + l15 * 8);
      float wb0 = bf2f((unsigned short)(b0 & 0xffffu));
      float wb1 = bf2f((unsigned short)(b1e & 0xffffu));
#pragma unroll
      for (int k = 0; k < 8; k++) accB[k] += bf2f(rb0[k]) * wb0;
#pragma unroll
      for (int k = 0; k < 8; k++) accB[k] += bf2f(rb1[k]) * wb1;
    }
    if (jB < eB) {
      unsigned b0 = edata[jB];
      ushort8v rb0 = *(const ushort8v*)(XWb + (size_t)(b0 >> 16) * NHID + l15 * 8);
      float wb0 = bf2f((unsigned short)(b0 & 0xffffu));
#pragma unroll
      for (int k = 0; k < 8; k++) accB[k] += bf2f(rb0[k]) * wb0;
    }
#pragma unroll
    for (int k = 0; k < 8; k++) {
      accA[k] += __shfl_down(accA[k], 32, 64);
      accA[k] += __shfl_down(accA[k], 16, 64);
      accB[k] += __shfl_down(accB[k], 32, 64);
      accB[k] += __shfl_down(accB[k], 16, 64);
    }
    if (lane < 16) {
      short8v sA, sB;
#pragma unroll
      for (int k = 0; k < 8; k++) {
        sA[k] = (short)f2bf(fmaxf(accA[k] + bb[k], 0.f));
        sB[k] = (short)f2bf(fmaxf(accB[k] + bb[k], 0.f));
      }
      *(short8v*)&A_lds[rA][l15 * 8] = sA;
      *(short8v*)&A_lds[rB][l15 * 8] = sB;
    }
  }
  __syncthreads();

  f32x4 acc2[4][2];
#pragma unroll
  for (int i = 0; i < 4; i++)
#pragma unroll
    for (int j = 0; j < 2; j++) acc2[i][j] = (f32x4){0.f, 0.f, 0.f, 0.f};

#pragma unroll
  for (int k0 = 0; k0 < NHID; k0 += 32) {
    bf16x8 a[4], b[2];
#pragma unroll
    for (int mt = 0; mt < 4; mt++)
      a[mt] = *(const bf16x8*)&A_lds[mt * 16 + l15][k0 + quad * 8];
#pragma unroll
    for (int nt = 0; nt < 2; nt++) {
      int n = wave * 32 + nt * 16 + l15;
      b[nt] = *(const bf16x8*)(WcT + (size_t)n * NHID + k0 + quad * 8);
    }
#pragma unroll
    for (int mt = 0; mt < 4; mt++)
#pragma unroll
      for (int nt = 0; nt < 2; nt++)
        acc2[mt][nt] = __builtin_amdgcn_mfma_f32_16x16x32_bf16(a[mt], b[nt], acc2[mt][nt], 0, 0, 0);
  }
#pragma unroll
  for (int mt = 0; mt < 4; mt++) {
#pragma unroll
    for (int reg = 0; reg < 4; reg++) {
      int gr = row0 + mt * 16 + quad * 4 + reg;
      if (gr < N_NODES) {
#pragma unroll
        for (int nt = 0; nt < 2; nt++) {
          int gc = wave * 32 + nt * 16 + l15;
          Tb[(size_t)gr * NHID + gc] = f2bf(acc2[mt][nt][reg]);
        }
      }
    }
  }
}

// ---------------------------------------------------------------------------
// Gather 2: one wave per TWO nodes, dual-node interleave.
// out_mu = bmu + sum Tb[src][0:64]*w ; out_lv cols 64:128.
// ---------------------------------------------------------------------------
__launch_bounds__(256)
__global__ void gather2_kernel(const unsigned short* __restrict__ Tb,
                               const int2* __restrict__ offs,
                               const unsigned int* __restrict__ edata,
                               const float* __restrict__ bmu,
                               const float* __restrict__ blv,
                               float* __restrict__ out) {
  int wv = (int)((blockIdx.x * blockDim.x + threadIdx.x) >> 6);
  int gA = wv * 2, gB = wv * 2 + 1;
  if (gA >= N_NODES) return;
  int lane = threadIdx.x & 63;
  int quad = lane >> 4;
  int c8 = lane & 15;
  float accA[8], accB[8];
#pragma unroll
  for (int k = 0; k < 8; k++) { accA[k] = 0.f; accB[k] = 0.f; }
  int jA = 0, eA = 0, jB = 0, eB = 0;
  { int2 o = offs[gA]; jA = o.x + quad; eA = o.y; }
  if (gB < N_NODES) { int2 o = offs[gB]; jB = o.x + quad; eB = o.y; }
  while (jA + 4 < eA && jB + 4 < eB) {
    unsigned a0 = edata[jA], a1 = edata[jA + 4];
    unsigned b0 = edata[jB], b1e = edata[jB + 4];
    ushort8v ra0 = *(const ushort8v*)(Tb + (size_t)(a0 >> 16) * NHID + c8 * 8);
    ushort8v ra1 = *(const ushort8v*)(Tb + (size_t)(a1 >> 16) * NHID + c8 * 8);
    ushort8v rb0 = *(const ushort8v*)(Tb + (size_t)(b0 >> 16) * NHID + c8 * 8);
    ushort8v rb1 = *(const ushort8v*)(Tb + (size_t)(b1e >> 16) * NHID + c8 * 8);
    float wa0 = bf2f((unsigned short)(a0 & 0xffffu));
    float wa1 = bf2f((unsigned short)(a1 & 0xffffu));
    float wb0 = bf2f((unsigned short)(b0 & 0xffffu));
    float wb1 = bf2f((unsigned short)(b1e & 0xffffu));
#pragma unroll
    for (int k = 0; k < 8; k++) accA[k] += bf2f(ra0[k]) * wa0;
#pragma unroll
    for (int k = 0; k < 8; k++) accA[k] += bf2f(ra1[k]) * wa1;
#pragma unroll
    for (int k = 0; k < 8; k++) accB[k] += bf2f(rb0[k]) * wb0;
#pragma unroll
    for (int k = 0; k < 8; k++) accB[k] += bf2f(rb1[k]) * wb1;
    jA += 8; jB += 8;
  }
  for (; jA + 4 < eA; jA += 8) {
    unsigned a0 = edata[jA], a1 = edata[jA + 4];
    ushort8v ra0 = *(const ushort8v*)(Tb + (size_t)(a0 >> 16) * NHID + c8 * 8);
    ushort8v ra1 = *(const ushort8v*)(Tb + (size_t)(a1 >> 16) * NHID + c8 * 8);
    float wa0 = bf2f((unsigned short)(a0 & 0xffffu));
    float wa1 = bf2f((unsigned short)(a1 & 0xffffu));
#pragma unroll
    for (int k = 0; k < 8; k++) accA[k] += bf2f(ra0[k]) * wa0;
#pragma unroll
    for (int k = 0; k < 8; k++) accA[k] += bf2f(ra1[k]) * wa1;
  }
  if (jA < eA) {
    unsigned a0 = edata[jA];
    ushort8v ra0 = *(const ushort8v*)(Tb + (size_t)(a0 >> 16) * NHID + c8 * 8);
    float wa0 = bf2f((unsigned short)(a0 & 0xffffu));
#pragma unroll
    for (int k = 0; k < 8; k++) accA[k] += bf2f(ra0[k]) * wa0;
  }
  for (; jB + 4 < eB; jB += 8) {
    unsigned b0 = edata[jB], b1e = edata[jB + 4];
    ushort8v rb0 = *(const ushort8v*)(Tb + (size_t)(b0 >> 16) * NHID + c8 * 8);
    ushort8v rb1 = *(const ushort8v*)(Tb + (size_t)(b1e >> 16) * NHID + c8 * 8);
    float wb0 = bf2f((unsigned short)(b0 & 0xffffu));
    float wb1 = bf2f((unsigned short)(b1e & 0xffffu));
#pragma unroll
    for (int k = 0; k < 8; k++) accB[k] += bf2f(rb0[k]) * wb0;
#pragma unroll
    for (int k = 0; k < 8; k++) accB[k] += bf2f(rb1[k]) * wb1;
  }
  if (jB < eB) {
    unsigned b0 = edata[jB];
    ushort8v rb0 = *(const ushort8v*)(Tb + (size_t)(b0 >> 16) * NHID + c8 * 8);
    float wb0 = bf2f((unsigned short)(b0 & 0xffffu));
#pragma unroll
    for (int k = 0; k < 8; k++) accB[k] += bf2f(rb0[k]) * wb0;
  }
#pragma unroll
  for (int k = 0; k < 8; k++) {
    accA[k] += __shfl_down(accA[k], 32, 64);
    accA[k] += __shfl_down(accA[k], 16, 64);
    accB[k] += __shfl_down(accB[k], 32, 64);
    accB[k] += __shfl_down(accB[k], 16, 64);
  }
  if (lane < 8) {
    const float* bp = bmu + c8 * 8;
    float4 b0 = *(const float4*)bp;
    float4 b1v = *(const float4*)(bp + 4);
    float* op = out + (size_t)gA * LATENT + c8 * 8;
    float4 o0, o1;
    o0.x = accA[0] + b0.x; o0.y = accA[1] + b0.y;
    o0.z = accA[2] + b0.z; o0.w = accA[3] + b0.w;
    o1.x = accA[4] + b1v.x; o1.y = accA[5] + b1v.y;
    o1.z = accA[6] + b1v.z; o1.w = accA[7] + b1v.w;
    *(float4*)op = o0;
    *(float4*)(op + 4) = o1;
    if (gB < N_NODES) {
      float* opB = out + (size_t)gB * LATENT + c8 * 8;
      float4 p0, p1;
      p0.x = accB[0] + b0.x; p0.y = accB[1] + b0.y;
      p0.z = accB[2] + b0.z; p0.w = accB[3] + b0.w;
      p1.x = accB[4] + b1v.x; p1.y = accB[5] + b1v.y;
      p1.z = accB[6] + b1v.z; p1.w = accB[7] + b1v.w;
      *(float4*)opB = p0;
      *(float4*)(opB + 4) = p1;
    }
  } else if (lane < 16) {
    int c = c8 - 8;
    const float* bp = blv + c * 8;
    float4 b0 = *(const float4*)bp;
    float4 b1v = *(const float4*)(bp + 4);
    float* op = out + (size_t)N_NODES * LATENT + (size_t)gA * LATENT + c * 8;
    float4 o0, o1;
    o0.x = accA[0] + b0.x; o0.y = accA[1] + b0.y;
    o0.z = accA[2] + b0.z; o0.w = accA[3] + b0.w;
    o1.x = accA[4] + b1v.x; o1.y = accA[5] + b1v.y;
    o1.z = accA[6] + b1v.z; o1.w = accA[7] + b1v.w;
    *(float4*)op = o0;
    *(float4*)(op + 4) = o1;
    if (gB < N_NODES) {
      float* opB = out + (size_t)N_NODES * LATENT + (size_t)gB * LATENT + c * 8;
      float4 p0, p1;
      p0.x = accB[0] + b0.x; p0.y = accB[1] + b0.y;
      p0.z = accB[2] + b0.z; p0.w = accB[3] + b0.w;
      p1.x = accB[4] + b1v.x; p1.y = accB[5] + b1v.y;
      p1.z = accB[6] + b1v.z; p1.w = accB[7] + b1v.w;
      *(float4*)opB = p0;
      *(float4*)(opB + 4) = p1;
    }
  }
}

extern "C" void kernel_launch(void* const* d_in, const int* in_sizes, int n_in,
                              void* d_out, int out_size, void* d_ws, size_t ws_size,
                              hipStream_t stream) {
  const float* x   = (const float*)d_in[0];
  const int*   src = (const int*)d_in[1];
  const int*   dst = (const int*)d_in[2];
  const float* ew  = (const float*)d_in[3];
  const float* W1  = (const float*)d_in[4];
  const float* b1  = (const float*)d_in[5];
  const float* Wmu = (const float*)d_in[6];
  const float* bmu = (const float*)d_in[7];
  const float* Wlv = (const float*)d_in[8];
  const float* blv = (const float*)d_in[9];
  float* out = (float*)d_out;

  unsigned short* XWb = (unsigned short*)d_ws;             // 12.8 MB
  unsigned short* Tbb = XWb + (size_t)N_NODES * NHID;      // 12.8 MB
  int2* part = (int2*)(Tbb + (size_t)N_NODES * NHID);      // 196*4608*8 = 7.2 MB
  unsigned int* edata = (unsigned int*)(part + (size_t)NB * CAP);  // 3.6 MB
  int2* offs = (int2*)(edata + (size_t)NB * CAP);          // 50176*8 = 401 KB
  int* bcur  = (int*)(offs + 50176);                       // 256 ints
  unsigned short* W1T = (unsigned short*)(bcur + 256);     // 64 KB
  unsigned short* WcT = W1T + 128 * NFEAT;                 // 32 KB

  dim3 blk(256);
  int wave_grid2 = ((N_NODES + 1) / 2 * 64 + 255) / 256;  // 6250

  prep_w_kernel<<<257, blk, 0, stream>>>(W1, Wmu, Wlv, W1T, WcT, bcur);
  gemm1_coarse_kernel<<<GEMM_GRID + CBLK, dim3(512), 0, stream>>>(
      x, W1T, XWb, src, dst, ew, bcur, part);
  fine_kernel<<<NB, dim3(512), 0, stream>>>(bcur, part, offs, edata);
  g1gemm2_kernel<<<GEMM_GRID, blk, 0, stream>>>(XWb, offs, edata, b1, WcT, Tbb);
  gather2_kernel<<<wave_grid2, blk, 0, stream>>>(Tbb, offs, edata, bmu, blv, out);
}